// Round 13
// baseline (228.035 us; speedup 1.0000x reference)
//
#include <hip/hip_runtime.h>
#include <math.h>

#define NB 512
#define LONGN 1000
#define SHORTN 50
#define TOPKN 50
#define HALFN 500
#define NG 8          // item-groups per hard block
#define EROW 72       // hard-path bf16 LDS row stride (shorts)
#define BROW 72       // bst bf16 row stride (shorts) for xbf/obf
#define F1ROW 136     // bst bf16 row stride for ff1 output (128+8)

typedef __attribute__((ext_vector_type(8))) short bf16x8;
typedef __attribute__((ext_vector_type(4))) float f32x4;

__device__ __forceinline__ float dot4(float4 a, float4 b) {
  return a.x*b.x + a.y*b.y + a.z*b.z + a.w*b.w;
}

template<int N>
__device__ __forceinline__ float dotN(const float* w, const float* x) {
  const float4* w4 = (const float4*)w;
  const float4* x4 = (const float4*)x;
  float a0 = 0.f, a1 = 0.f, a2 = 0.f, a3 = 0.f;
  #pragma unroll
  for (int k = 0; k < N/4; k += 4) {
    a0 += dot4(w4[k],   x4[k]);
    a1 += dot4(w4[k+1], x4[k+1]);
    a2 += dot4(w4[k+2], x4[k+2]);
    a3 += dot4(w4[k+3], x4[k+3]);
  }
  return (a0 + a1) + (a2 + a3);
}

__device__ __forceinline__ float wave_sum(float v) {
  #pragma unroll
  for (int off = 32; off > 0; off >>= 1) v += __shfl_xor(v, off);
  return v;
}
__device__ __forceinline__ float wave_max(float v) {
  #pragma unroll
  for (int off = 32; off > 0; off >>= 1) v = fmaxf(v, __shfl_xor(v, off));
  return v;
}

__device__ __forceinline__ unsigned short f2bf(float x) {  // RNE fp32->bf16
  unsigned u = __float_as_uint(x);
  return (unsigned short)((u + 0x7fffu + ((u >> 16) & 1u)) >> 16);
}

// ===========================================================================
// K1 (MFMA): hard-search scores. (R9 version, f32 gather)
// ===========================================================================
__global__ __launch_bounds__(256, 3) void hard_scores_kernel(
    const int* __restrict__ target_item_id,
    const int* __restrict__ long_hist_ids,
    const float* __restrict__ item_emb,
    const float* __restrict__ tproj_w, const float* __restrict__ tproj_b,
    const float* __restrict__ attn_w1, const float* __restrict__ attn_b1,
    const float* __restrict__ attn_w2, const float* __restrict__ attn_b2,
    const float* __restrict__ hash_emb,
    float* __restrict__ scores_ws, float* __restrict__ partA,
    float* __restrict__ partH)
{
  __shared__ __align__(16) short Abf[64*EROW];
  __shared__ __align__(16) short Ebuf[2][64*EROW];
  __shared__ __align__(16) float tv[64];
  __shared__ __align__(16) float te[64];
  __shared__ __align__(16) float2 cw[64];
  __shared__ int idsL[HALFN];
  __shared__ __align__(16) float redE[4*64];

  const int bid = blockIdx.x;
  const int b = bid >> 1, half = bid & 1;
  const int base = half * HALFN;
  const int tid = threadIdx.x;
  const int wid = tid >> 6, lane = tid & 63;

  if (tid < 64) tv[tid] = item_emb[target_item_id[b]*64 + tid];
  for (int l = tid; l < HALFN; l += 256) idsL[l] = long_hist_ids[b*LONGN + base + l];
  __syncthreads();
  if (tid < 64) te[tid] = tproj_b[tid] + dotN<64>(tproj_w + tid*64, tv);
  __syncthreads();
  if (tid < 64) {
    float c = attn_b1[tid] + dotN<64>(attn_w1 + tid*192, te);
    cw[tid] = make_float2(c, attn_w2[tid]);
  }
  for (int idx = tid; idx < 4096; idx += 256) {
    int i = idx >> 6, j = idx & 63;
    Abf[i*EROW + j] = (short)f2bf(attn_w1[i*192 + 64 + j] + attn_w1[i*192 + 128 + j]*te[j]);
  }
  __syncthreads();

  bf16x8 a00,a01,a10,a11,a20,a21,a30,a31;
  {
    const short* ap = Abf + (lane & 15)*EROW + ((lane >> 4) << 3);
    a00 = *(const bf16x8*)(ap +  0*EROW);  a01 = *(const bf16x8*)(ap +  0*EROW + 32);
    a10 = *(const bf16x8*)(ap + 16*EROW);  a11 = *(const bf16x8*)(ap + 16*EROW + 32);
    a20 = *(const bf16x8*)(ap + 32*EROW);  a21 = *(const bf16x8*)(ap + 32*EROW + 32);
    a30 = *(const bf16x8*)(ap + 48*EROW);  a31 = *(const bf16x8*)(ap + 48*EROW + 32);
  }

  const float b2s = attn_b2[0];
  const int it_g = tid >> 2;
  const int dimg = (tid & 3) * 16;

  float4 sE0 = {0,0,0,0}, sE1 = {0,0,0,0}, sE2 = {0,0,0,0}, sE3 = {0,0,0,0};

  {
    const float4* ep = (const float4*)(item_emb + (size_t)idsL[it_g]*64 + dimg);
    float4 r0 = ep[0], r1 = ep[1], r2 = ep[2], r3 = ep[3];
    sE0.x+=r0.x; sE0.y+=r0.y; sE0.z+=r0.z; sE0.w+=r0.w;
    sE1.x+=r1.x; sE1.y+=r1.y; sE1.z+=r1.z; sE1.w+=r1.w;
    sE2.x+=r2.x; sE2.y+=r2.y; sE2.z+=r2.z; sE2.w+=r2.w;
    sE3.x+=r3.x; sE3.y+=r3.y; sE3.z+=r3.z; sE3.w+=r3.w;
    bf16x8 w0, w1;
    w0[0]=(short)f2bf(r0.x); w0[1]=(short)f2bf(r0.y); w0[2]=(short)f2bf(r0.z); w0[3]=(short)f2bf(r0.w);
    w0[4]=(short)f2bf(r1.x); w0[5]=(short)f2bf(r1.y); w0[6]=(short)f2bf(r1.z); w0[7]=(short)f2bf(r1.w);
    w1[0]=(short)f2bf(r2.x); w1[1]=(short)f2bf(r2.y); w1[2]=(short)f2bf(r2.z); w1[3]=(short)f2bf(r2.w);
    w1[4]=(short)f2bf(r3.x); w1[5]=(short)f2bf(r3.y); w1[6]=(short)f2bf(r3.z); w1[7]=(short)f2bf(r3.w);
    short* dst = &Ebuf[0][it_g*EROW + dimg];
    *(bf16x8*)dst = w0;  *(bf16x8*)(dst + 8) = w1;
  }
  __syncthreads();

  int buf = 0;
  for (int g = 0; g < NG; ++g) {
    float4 r0={0,0,0,0}, r1={0,0,0,0}, r2={0,0,0,0}, r3={0,0,0,0};
    const bool more = (g + 1 < NG);
    if (more) {
      const int gi = (g+1)*64 + it_g;
      if (gi < HALFN) {
        const float4* ep = (const float4*)(item_emb + (size_t)idsL[gi]*64 + dimg);
        r0 = ep[0]; r1 = ep[1]; r2 = ep[2]; r3 = ep[3];
      }
    }

    f32x4 acc0={0,0,0,0}, acc1={0,0,0,0}, acc2={0,0,0,0}, acc3={0,0,0,0};
    {
      const short* ep = &Ebuf[buf][(wid*16 + (lane & 15))*EROW + ((lane >> 4) << 3)];
      bf16x8 b0 = *(const bf16x8*)(ep);
      bf16x8 b1 = *(const bf16x8*)(ep + 32);
      acc0 = __builtin_amdgcn_mfma_f32_16x16x32_bf16(a00, b0, acc0, 0, 0, 0);
      acc0 = __builtin_amdgcn_mfma_f32_16x16x32_bf16(a01, b1, acc0, 0, 0, 0);
      acc1 = __builtin_amdgcn_mfma_f32_16x16x32_bf16(a10, b0, acc1, 0, 0, 0);
      acc1 = __builtin_amdgcn_mfma_f32_16x16x32_bf16(a11, b1, acc1, 0, 0, 0);
      acc2 = __builtin_amdgcn_mfma_f32_16x16x32_bf16(a20, b0, acc2, 0, 0, 0);
      acc2 = __builtin_amdgcn_mfma_f32_16x16x32_bf16(a21, b1, acc2, 0, 0, 0);
      acc3 = __builtin_amdgcn_mfma_f32_16x16x32_bf16(a30, b0, acc3, 0, 0, 0);
      acc3 = __builtin_amdgcn_mfma_f32_16x16x32_bf16(a31, b1, acc3, 0, 0, 0);
    }
    float p = 0.f;
    {
      const int rbase = (lane >> 4) << 2;
      #pragma unroll
      for (int r = 0; r < 4; ++r) {
        float2 c0 = cw[ 0 + rbase + r];
        float2 c1 = cw[16 + rbase + r];
        float2 c2 = cw[32 + rbase + r];
        float2 c3 = cw[48 + rbase + r];
        p += c0.y * fmaxf(acc0[r] + c0.x, 0.f);
        p += c1.y * fmaxf(acc1[r] + c1.x, 0.f);
        p += c2.y * fmaxf(acc2[r] + c2.x, 0.f);
        p += c3.y * fmaxf(acc3[r] + c3.x, 0.f);
      }
    }
    p += __shfl_xor(p, 16);
    p += __shfl_xor(p, 32);
    if (lane < 16) {
      const int gi = g*64 + wid*16 + lane;
      if (gi < HALFN) scores_ws[b*LONGN + base + gi] = b2s + p;
    }

    if (more) {
      sE0.x+=r0.x; sE0.y+=r0.y; sE0.z+=r0.z; sE0.w+=r0.w;
      sE1.x+=r1.x; sE1.y+=r1.y; sE1.z+=r1.z; sE1.w+=r1.w;
      sE2.x+=r2.x; sE2.y+=r2.y; sE2.z+=r2.z; sE2.w+=r2.w;
      sE3.x+=r3.x; sE3.y+=r3.y; sE3.z+=r3.z; sE3.w+=r3.w;
      bf16x8 w0, w1;
      w0[0]=(short)f2bf(r0.x); w0[1]=(short)f2bf(r0.y); w0[2]=(short)f2bf(r0.z); w0[3]=(short)f2bf(r0.w);
      w0[4]=(short)f2bf(r1.x); w0[5]=(short)f2bf(r1.y); w0[6]=(short)f2bf(r1.z); w0[7]=(short)f2bf(r1.w);
      w1[0]=(short)f2bf(r2.x); w1[1]=(short)f2bf(r2.y); w1[2]=(short)f2bf(r2.z); w1[3]=(short)f2bf(r2.w);
      w1[4]=(short)f2bf(r3.x); w1[5]=(short)f2bf(r3.y); w1[6]=(short)f2bf(r3.z); w1[7]=(short)f2bf(r3.w);
      short* dst = &Ebuf[buf ^ 1][it_g*EROW + dimg];
      *(bf16x8*)dst = w0;  *(bf16x8*)(dst + 8) = w1;
    }
    __syncthreads();
    buf ^= 1;
  }

  {
    float* red = (float*)&Ebuf[0][0];
    const int b17 = tid * 17;
    red[b17+ 0]=sE0.x; red[b17+ 1]=sE0.y; red[b17+ 2]=sE0.z; red[b17+ 3]=sE0.w;
    red[b17+ 4]=sE1.x; red[b17+ 5]=sE1.y; red[b17+ 6]=sE1.z; red[b17+ 7]=sE1.w;
    red[b17+ 8]=sE2.x; red[b17+ 9]=sE2.y; red[b17+10]=sE2.z; red[b17+11]=sE2.w;
    red[b17+12]=sE3.x; red[b17+13]=sE3.y; red[b17+14]=sE3.z; red[b17+15]=sE3.w;
    __syncthreads();
    if (tid < 64) {
      const int dg = tid >> 4, dw = tid & 15;
      float s = 0.f;
      for (int j = 0; j < 64; ++j) s += red[(j*4 + dg)*17 + dw];
      partA[bid*64 + tid] = s;
    }
  }

  {
    const int hl = lane >> 4, dd = lane & 15;
    const float* hb = hash_emb + hl*1024*16 + dd;
    float accH = 0.f;
    for (int l = wid; l < HALFN; l += 4)
      accH += hb[(idsL[l] & 1023)*16];
    redE[wid*64 + lane] = accH;
  }
  __syncthreads();
  if (wid == 0)
    partH[bid*64 + lane] = redE[lane] + redE[64+lane] + redE[128+lane] + redE[192+lane];
}

// ===========================================================================
// BST weight prep (unchanged).
// ===========================================================================
__global__ __launch_bounds__(256) void bst_prep_kernel(
    const float* __restrict__ qkv_w, const float* __restrict__ out_w,
    const float* __restrict__ ff1_w, const float* __restrict__ ff2_w,
    short* __restrict__ wF)
{
  const int t = blockIdx.x*256 + threadIdx.x;   // 8192 threads
  if (t >= 8192) return;
  const int fid = t >> 6, lane = t & 63;
  const int n16 = lane & 15, k8 = (lane >> 4) * 8;
  const float* src;
  if (fid < 48)      { int f=fid,    l=f/24, r=f%24, nt=r>>1, kc=r&1;
    src = qkv_w + l*12288 + (nt*16+n16)*64 + kc*32 + k8; }
  else if (fid < 64) { int f=fid-48, l=f>>3, r=f&7,  nt=r>>1, kc=r&1;
    src = out_w + l*4096 + (nt*16+n16)*64 + kc*32 + k8; }
  else if (fid < 96) { int f=fid-64, l=f>>4, r=f&15, nt=r>>1, kc=r&1;
    src = ff1_w + l*8192 + (nt*16+n16)*64 + kc*32 + k8; }
  else               { int f=fid-96, l=f>>4, r=f&15, nt=r>>2, kc=r&3;
    src = ff2_w + l*8192 + (nt*16+n16)*128 + kc*32 + k8; }
  short* dst = wF + fid*512 + lane*8;
  #pragma unroll
  for (int j = 0; j < 8; ++j) dst[j] = (short)f2bf(src[j]);
}

// ===========================================================================
// BST transformer v8: MFMA GEMMs + 2-wave concentrated attention (2 s-rows
// per lane, no-max softmax -- scores are tiny so exp cannot overflow and
// softmax is scale-invariant). f32 k/v (R11 showed bf16 unpack hurts).
// ===========================================================================
__global__ __launch_bounds__(256) void bst_kernel(
    const int* __restrict__ short_ids, const float* __restrict__ item_emb,
    const short* __restrict__ wF,
    const float* __restrict__ qkv_b, const float* __restrict__ out_b,
    const float* __restrict__ ln1_g, const float* __restrict__ ln1_b,
    const float* __restrict__ ff1_b, const float* __restrict__ ff2_b,
    const float* __restrict__ ln2_g, const float* __restrict__ ln2_b,
    float* __restrict__ bst_out)
{
  __shared__ __align__(16) float xf[SHORTN*64];
  __shared__ __align__(16) short xbf[64*BROW];
  __shared__ __align__(16) float qf[SHORTN*68];
  __shared__ __align__(16) float arena[SHORTN*132];
  __shared__ __align__(16) short obf[64*BROW];

  short* f1bf = (short*)arena;

  const int b = blockIdx.x, tid = threadIdx.x;
  const int wid = tid >> 6, lane = tid & 63;
  const int n16 = lane & 15;
  const int kg8 = (lane >> 4) << 3;
  const int mrow = (lane >> 4) << 2;

  for (int idx = tid; idx < SHORTN*64; idx += 256) {
    int s = idx >> 6, j = idx & 63;
    float v = item_emb[short_ids[b*SHORTN + s]*64 + j];
    xf[idx] = v;
    xbf[s*BROW + j] = (short)f2bf(v);
  }
  for (int idx = tid; idx < 14*BROW; idx += 256) {
    xbf[50*BROW + idx] = 0;
    obf[50*BROW + idx] = 0;
  }
  __syncthreads();

  for (int l = 0; l < 2; ++l) {
    // ======== qkv ========
    {
      const short* ap = xbf + n16*BROW + kg8;
      bf16x8 A00 = *(const bf16x8*)(ap);            bf16x8 A01 = *(const bf16x8*)(ap + 32);
      bf16x8 A10 = *(const bf16x8*)(ap + 16*BROW);  bf16x8 A11 = *(const bf16x8*)(ap + 16*BROW + 32);
      bf16x8 A20 = *(const bf16x8*)(ap + 32*BROW);  bf16x8 A21 = *(const bf16x8*)(ap + 32*BROW + 32);
      bf16x8 A30 = *(const bf16x8*)(ap + 48*BROW);  bf16x8 A31 = *(const bf16x8*)(ap + 48*BROW + 32);
      #pragma unroll
      for (int t = 0; t < 3; ++t) {
        const int nt = wid*3 + t;
        const short* bp = wF + (size_t)(l*24 + nt*2)*512 + lane*8;
        bf16x8 B0 = *(const bf16x8*)(bp);
        bf16x8 B1 = *(const bf16x8*)(bp + 512);
        f32x4 c0={0,0,0,0}, c1={0,0,0,0}, c2={0,0,0,0}, c3={0,0,0,0};
        c0 = __builtin_amdgcn_mfma_f32_16x16x32_bf16(A00, B0, c0, 0,0,0);
        c0 = __builtin_amdgcn_mfma_f32_16x16x32_bf16(A01, B1, c0, 0,0,0);
        c1 = __builtin_amdgcn_mfma_f32_16x16x32_bf16(A10, B0, c1, 0,0,0);
        c1 = __builtin_amdgcn_mfma_f32_16x16x32_bf16(A11, B1, c1, 0,0,0);
        c2 = __builtin_amdgcn_mfma_f32_16x16x32_bf16(A20, B0, c2, 0,0,0);
        c2 = __builtin_amdgcn_mfma_f32_16x16x32_bf16(A21, B1, c2, 0,0,0);
        c3 = __builtin_amdgcn_mfma_f32_16x16x32_bf16(A30, B0, c3, 0,0,0);
        c3 = __builtin_amdgcn_mfma_f32_16x16x32_bf16(A31, B1, c3, 0,0,0);
        const int c = nt*16 + n16;
        const float bias = qkv_b[l*192 + c];
        #pragma unroll
        for (int r = 0; r < 4; ++r) {
          int m0 = mrow + r;
          float v0 = c0[r] + bias;
          float v1 = c1[r] + bias;
          float v2 = c2[r] + bias;
          float v3 = c3[r] + bias;
          if (c < 64) {
            qf[m0*68 + c] = v0;
            if (m0+16 < SHORTN) qf[(m0+16)*68 + c] = v1;
            if (m0+32 < SHORTN) qf[(m0+32)*68 + c] = v2;
            if (m0+48 < SHORTN) qf[(m0+48)*68 + c] = v3;
          } else {
            const int cc = c - 64;
            arena[m0*132 + cc] = v0;
            if (m0+16 < SHORTN) arena[(m0+16)*132 + cc] = v1;
            if (m0+32 < SHORTN) arena[(m0+32)*132 + cc] = v2;
            if (m0+48 < SHORTN) arena[(m0+48)*132 + cc] = v3;
          }
        }
      }
    }
    __syncthreads();

    // ======== attention: 2 waves, head = 2*w + (lane>>5), 2 s-rows/lane,
    //          no-max softmax (scores tiny; scale-invariant) ========
    if (tid < 128) {
      const int h = ((tid >> 6) << 1) + ((lane >> 5) & 1);
      const int g = lane & 31;
      if (g < 25) {
        const int s0 = 2*g, s1 = 2*g + 1;
        const float4* qp0 = (const float4*)(qf + s0*68 + h*16);
        const float4* qp1 = (const float4*)(qf + s1*68 + h*16);
        const float4 qa0 = qp0[0], qb0 = qp0[1], qc0 = qp0[2], qd0 = qp0[3];
        const float4 qa1 = qp1[0], qb1 = qp1[1], qc1 = qp1[2], qd1 = qp1[3];
        float ss0 = 0.f, ss1 = 0.f;
        float4 o00={0,0,0,0},o01={0,0,0,0},o02={0,0,0,0},o03={0,0,0,0};
        float4 o10={0,0,0,0},o11={0,0,0,0},o12={0,0,0,0},o13={0,0,0,0};
        for (int t2 = 0; t2 < SHORTN; ++t2) {
          const float4* kp = (const float4*)(arena + t2*132 + h*16);
          float4 k0 = kp[0], k1 = kp[1], k2 = kp[2], k3 = kp[3];
          float d0 = dot4(qa0,k0) + dot4(qb0,k1) + dot4(qc0,k2) + dot4(qd0,k3);
          float d1 = dot4(qa1,k0) + dot4(qb1,k1) + dot4(qc1,k2) + dot4(qd1,k3);
          float p0 = __expf(d0*0.25f);
          float p1 = __expf(d1*0.25f);
          ss0 += p0;  ss1 += p1;
          const float4* vp = (const float4*)(arena + t2*132 + 64 + h*16);
          float4 v0 = vp[0], v1 = vp[1], v2 = vp[2], v3 = vp[3];
          o00.x += p0*v0.x; o00.y += p0*v0.y; o00.z += p0*v0.z; o00.w += p0*v0.w;
          o01.x += p0*v1.x; o01.y += p0*v1.y; o01.z += p0*v1.z; o01.w += p0*v1.w;
          o02.x += p0*v2.x; o02.y += p0*v2.y; o02.z += p0*v2.z; o02.w += p0*v2.w;
          o03.x += p0*v3.x; o03.y += p0*v3.y; o03.z += p0*v3.z; o03.w += p0*v3.w;
          o10.x += p1*v0.x; o10.y += p1*v0.y; o10.z += p1*v0.z; o10.w += p1*v0.w;
          o11.x += p1*v1.x; o11.y += p1*v1.y; o11.z += p1*v1.z; o11.w += p1*v1.w;
          o12.x += p1*v2.x; o12.y += p1*v2.y; o12.z += p1*v2.z; o12.w += p1*v2.w;
          o13.x += p1*v3.x; o13.y += p1*v3.y; o13.z += p1*v3.z; o13.w += p1*v3.w;
        }
        const float i0 = 1.f/ss0, i1 = 1.f/ss1;
        bf16x8 w0, w1;
        w0[0]=(short)f2bf(o00.x*i0); w0[1]=(short)f2bf(o00.y*i0);
        w0[2]=(short)f2bf(o00.z*i0); w0[3]=(short)f2bf(o00.w*i0);
        w0[4]=(short)f2bf(o01.x*i0); w0[5]=(short)f2bf(o01.y*i0);
        w0[6]=(short)f2bf(o01.z*i0); w0[7]=(short)f2bf(o01.w*i0);
        w1[0]=(short)f2bf(o02.x*i0); w1[1]=(short)f2bf(o02.y*i0);
        w1[2]=(short)f2bf(o02.z*i0); w1[3]=(short)f2bf(o02.w*i0);
        w1[4]=(short)f2bf(o03.x*i0); w1[5]=(short)f2bf(o03.y*i0);
        w1[6]=(short)f2bf(o03.z*i0); w1[7]=(short)f2bf(o03.w*i0);
        short* op0 = obf + s0*BROW + h*16;
        *(bf16x8*)op0 = w0;  *(bf16x8*)(op0 + 8) = w1;
        bf16x8 u0, u1;
        u0[0]=(short)f2bf(o10.x*i1); u0[1]=(short)f2bf(o10.y*i1);
        u0[2]=(short)f2bf(o10.z*i1); u0[3]=(short)f2bf(o10.w*i1);
        u0[4]=(short)f2bf(o11.x*i1); u0[5]=(short)f2bf(o11.y*i1);
        u0[6]=(short)f2bf(o11.z*i1); u0[7]=(short)f2bf(o11.w*i1);
        u1[0]=(short)f2bf(o12.x*i1); u1[1]=(short)f2bf(o12.y*i1);
        u1[2]=(short)f2bf(o12.z*i1); u1[3]=(short)f2bf(o12.w*i1);
        u1[4]=(short)f2bf(o13.x*i1); u1[5]=(short)f2bf(o13.y*i1);
        u1[6]=(short)f2bf(o13.z*i1); u1[7]=(short)f2bf(o13.w*i1);
        short* op1 = obf + s1*BROW + h*16;
        *(bf16x8*)op1 = u0;  *(bf16x8*)(op1 + 8) = u1;
      }
    }
    __syncthreads();

    // ======== out-proj + y ========
    {
      const short* ap = obf + n16*BROW + kg8;
      bf16x8 A00 = *(const bf16x8*)(ap);            bf16x8 A01 = *(const bf16x8*)(ap + 32);
      bf16x8 A10 = *(const bf16x8*)(ap + 16*BROW);  bf16x8 A11 = *(const bf16x8*)(ap + 16*BROW + 32);
      bf16x8 A20 = *(const bf16x8*)(ap + 32*BROW);  bf16x8 A21 = *(const bf16x8*)(ap + 32*BROW + 32);
      bf16x8 A30 = *(const bf16x8*)(ap + 48*BROW);  bf16x8 A31 = *(const bf16x8*)(ap + 48*BROW + 32);
      const int nt = wid;
      const short* bp = wF + (size_t)(48 + l*8 + nt*2)*512 + lane*8;
      bf16x8 B0 = *(const bf16x8*)(bp);
      bf16x8 B1 = *(const bf16x8*)(bp + 512);
      f32x4 c0={0,0,0,0}, c1={0,0,0,0}, c2={0,0,0,0}, c3={0,0,0,0};
      c0 = __builtin_amdgcn_mfma_f32_16x16x32_bf16(A00, B0, c0, 0,0,0);
      c0 = __builtin_amdgcn_mfma_f32_16x16x32_bf16(A01, B1, c0, 0,0,0);
      c1 = __builtin_amdgcn_mfma_f32_16x16x32_bf16(A10, B0, c1, 0,0,0);
      c1 = __builtin_amdgcn_mfma_f32_16x16x32_bf16(A11, B1, c1, 0,0,0);
      c2 = __builtin_amdgcn_mfma_f32_16x16x32_bf16(A20, B0, c2, 0,0,0);
      c2 = __builtin_amdgcn_mfma_f32_16x16x32_bf16(A21, B1, c2, 0,0,0);
      c3 = __builtin_amdgcn_mfma_f32_16x16x32_bf16(A30, B0, c3, 0,0,0);
      c3 = __builtin_amdgcn_mfma_f32_16x16x32_bf16(A31, B1, c3, 0,0,0);
      const int c = nt*16 + n16;
      const float bias = out_b[l*64 + c];
      #pragma unroll
      for (int r = 0; r < 4; ++r) {
        int m0 = mrow + r;
        arena[m0*68 + c] = xf[m0*64 + c] + bias + c0[r];
        if (m0+16 < SHORTN) arena[(m0+16)*68 + c] = xf[(m0+16)*64 + c] + bias + c1[r];
        if (m0+32 < SHORTN) arena[(m0+32)*68 + c] = xf[(m0+32)*64 + c] + bias + c2[r];
        if (m0+48 < SHORTN) arena[(m0+48)*68 + c] = xf[(m0+48)*64 + c] + bias + c3[r];
      }
      for (int idx = tid; idx < 14*F1ROW; idx += 256) f1bf[50*F1ROW + idx] = 0;
    }
    __syncthreads();

    // ======== LN1 ========
    {
      const float g = ln1_g[l*64 + lane], bb = ln1_b[l*64 + lane];
      for (int s = wid; s < SHORTN; s += 4) {
        float y = arena[s*68 + lane];
        float mean = wave_sum(y) * (1.f/64.f);
        float dv = y - mean;
        float var = wave_sum(dv*dv) * (1.f/64.f);
        float r = dv / sqrtf(var + 1e-5f) * g + bb;
        xf[s*64 + lane] = r;
        xbf[s*BROW + lane] = (short)f2bf(r);
      }
    }
    __syncthreads();

    // ======== ff1 ========
    {
      const short* ap = xbf + n16*BROW + kg8;
      bf16x8 A00 = *(const bf16x8*)(ap);            bf16x8 A01 = *(const bf16x8*)(ap + 32);
      bf16x8 A10 = *(const bf16x8*)(ap + 16*BROW);  bf16x8 A11 = *(const bf16x8*)(ap + 16*BROW + 32);
      bf16x8 A20 = *(const bf16x8*)(ap + 32*BROW);  bf16x8 A21 = *(const bf16x8*)(ap + 32*BROW + 32);
      bf16x8 A30 = *(const bf16x8*)(ap + 48*BROW);  bf16x8 A31 = *(const bf16x8*)(ap + 48*BROW + 32);
      #pragma unroll
      for (int t = 0; t < 2; ++t) {
        const int nt = wid*2 + t;
        const short* bp = wF + (size_t)(64 + l*16 + nt*2)*512 + lane*8;
        bf16x8 B0 = *(const bf16x8*)(bp);
        bf16x8 B1 = *(const bf16x8*)(bp + 512);
        f32x4 c0={0,0,0,0}, c1={0,0,0,0}, c2={0,0,0,0}, c3={0,0,0,0};
        c0 = __builtin_amdgcn_mfma_f32_16x16x32_bf16(A00, B0, c0, 0,0,0);
        c0 = __builtin_amdgcn_mfma_f32_16x16x32_bf16(A01, B1, c0, 0,0,0);
        c1 = __builtin_amdgcn_mfma_f32_16x16x32_bf16(A10, B0, c1, 0,0,0);
        c1 = __builtin_amdgcn_mfma_f32_16x16x32_bf16(A11, B1, c1, 0,0,0);
        c2 = __builtin_amdgcn_mfma_f32_16x16x32_bf16(A20, B0, c2, 0,0,0);
        c2 = __builtin_amdgcn_mfma_f32_16x16x32_bf16(A21, B1, c2, 0,0,0);
        c3 = __builtin_amdgcn_mfma_f32_16x16x32_bf16(A30, B0, c3, 0,0,0);
        c3 = __builtin_amdgcn_mfma_f32_16x16x32_bf16(A31, B1, c3, 0,0,0);
        const int c = nt*16 + n16;
        const float bias = ff1_b[l*128 + c];
        #pragma unroll
        for (int r = 0; r < 4; ++r) {
          int m0 = mrow + r;
          f1bf[m0*F1ROW + c] = (short)f2bf(fmaxf(c0[r] + bias, 0.f));
          if (m0+16 < SHORTN) f1bf[(m0+16)*F1ROW + c] = (short)f2bf(fmaxf(c1[r] + bias, 0.f));
          if (m0+32 < SHORTN) f1bf[(m0+32)*F1ROW + c] = (short)f2bf(fmaxf(c2[r] + bias, 0.f));
          if (m0+48 < SHORTN) f1bf[(m0+48)*F1ROW + c] = (short)f2bf(fmaxf(c3[r] + bias, 0.f));
        }
      }
    }
    __syncthreads();

    // ======== ff2 ========
    {
      const int nt = wid;
      f32x4 c0={0,0,0,0}, c1={0,0,0,0}, c2={0,0,0,0}, c3={0,0,0,0};
      #pragma unroll
      for (int kc = 0; kc < 4; ++kc) {
        const short* ap = f1bf + n16*F1ROW + kc*32 + kg8;
        bf16x8 A0 = *(const bf16x8*)(ap);
        bf16x8 A1 = *(const bf16x8*)(ap + 16*F1ROW);
        bf16x8 A2 = *(const bf16x8*)(ap + 32*F1ROW);
        bf16x8 A3 = *(const bf16x8*)(ap + 48*F1ROW);
        const short* bp = wF + (size_t)(96 + l*16 + nt*4 + kc)*512 + lane*8;
        bf16x8 B = *(const bf16x8*)(bp);
        c0 = __builtin_amdgcn_mfma_f32_16x16x32_bf16(A0, B, c0, 0,0,0);
        c1 = __builtin_amdgcn_mfma_f32_16x16x32_bf16(A1, B, c1, 0,0,0);
        c2 = __builtin_amdgcn_mfma_f32_16x16x32_bf16(A2, B, c2, 0,0,0);
        c3 = __builtin_amdgcn_mfma_f32_16x16x32_bf16(A3, B, c3, 0,0,0);
      }
      __syncthreads();
      const int c = nt*16 + n16;
      const float bias = ff2_b[l*64 + c];
      #pragma unroll
      for (int r = 0; r < 4; ++r) {
        int m0 = mrow + r;
        arena[m0*68 + c] = xf[m0*64 + c] + bias + c0[r];
        if (m0+16 < SHORTN) arena[(m0+16)*68 + c] = xf[(m0+16)*64 + c] + bias + c1[r];
        if (m0+32 < SHORTN) arena[(m0+32)*68 + c] = xf[(m0+32)*64 + c] + bias + c2[r];
        if (m0+48 < SHORTN) arena[(m0+48)*68 + c] = xf[(m0+48)*64 + c] + bias + c3[r];
      }
    }
    __syncthreads();

    // ======== LN2 ========
    {
      const float g = ln2_g[l*64 + lane], bb = ln2_b[l*64 + lane];
      for (int s = wid; s < SHORTN; s += 4) {
        float y = arena[s*68 + lane];
        float mean = wave_sum(y) * (1.f/64.f);
        float dv = y - mean;
        float var = wave_sum(dv*dv) * (1.f/64.f);
        float r = dv / sqrtf(var + 1e-5f) * g + bb;
        xf[s*64 + lane] = r;
        xbf[s*BROW + lane] = (short)f2bf(r);
      }
    }
    __syncthreads();
  }

  float acc = 0.f;
  for (int s = wid; s < SHORTN; s += 4) acc += xf[s*64 + lane];
  qf[wid*64 + lane] = acc;
  __syncthreads();
  if (wid == 0)
    bst_out[b*64 + lane] = (qf[lane] + qf[64+lane] + qf[128+lane] + qf[192+lane]) * (1.f/50.f);
}

// ===========================================================================
// K2+K4 merged: softmax(1000) + bitonic top-50 + re-softmax + hard/soft repr
// kept in LDS + fusion MLP -> final out. grid = NB. (unchanged from R12)
// ===========================================================================
__global__ __launch_bounds__(256) void hard_finish_fusion_kernel(
    const int* __restrict__ long_hist_ids,
    const float* __restrict__ item_emb,
    const float* __restrict__ sdim_w, const float* __restrict__ sdim_b,
    const float* __restrict__ scores_ws,
    const float* __restrict__ partA, const float* __restrict__ partH,
    const float* __restrict__ user, const float* __restrict__ bst,
    const float* __restrict__ w1, const float* __restrict__ b1,
    const float* __restrict__ w2, const float* __restrict__ b2,
    const float* __restrict__ w3, const float* __restrict__ b3,
    float* __restrict__ out)
{
  __shared__ __align__(16) float scores[LONGN];
  __shared__ int   idsL[LONGN];
  __shared__ __align__(16) unsigned long long kv[1024];
  __shared__ __align__(16) float redE[4*64];
  __shared__ __align__(16) float vecbuf[64];
  __shared__ float redV[4];
  __shared__ float selV[TOPKN];
  __shared__ int   selI[TOPKN];
  __shared__ __align__(16) float comb[256];
  __shared__ __align__(16) float h1[256];
  __shared__ __align__(16) float h2[128];

  const int b = blockIdx.x;
  const int tid = threadIdx.x;
  const int wid = tid >> 6, lane = tid & 63;

  for (int l = tid; l < LONGN; l += 256) {
    scores[l] = scores_ws[b*LONGN + l];
    idsL[l] = long_hist_ids[b*LONGN + l];
  }
  if (tid < 64)       comb[tid] = user[b*64 + tid];
  else if (tid >= 192) comb[tid] = bst[b*64 + tid - 192];
  __syncthreads();

  if (tid < 64)
    vecbuf[tid] = (partA[(2*b)*64 + tid] + partA[(2*b+1)*64 + tid]
                 + partH[(2*b)*64 + tid] + partH[(2*b+1)*64 + tid]) * (1.f/1000.f);
  __syncthreads();
  if (tid < 64)
    comb[128 + tid] = sdim_b[tid] + dotN<64>(sdim_w + tid*64, vecbuf);

  float mx = -INFINITY;
  for (int l = tid; l < LONGN; l += 256) mx = fmaxf(mx, scores[l]);
  mx = wave_max(mx);
  if (lane == 0) redV[wid] = mx;
  __syncthreads();
  mx = fmaxf(fmaxf(redV[0], redV[1]), fmaxf(redV[2], redV[3]));
  __syncthreads();
  float sm = 0.f;
  for (int l = tid; l < LONGN; l += 256) {
    float a = expf(scores[l] - mx);
    scores[l] = a;
    sm += a;
  }
  sm = wave_sum(sm);
  if (lane == 0) redV[wid] = sm;
  __syncthreads();
  {
    const float inv = 1.f / (redV[0] + redV[1] + redV[2] + redV[3]);
    for (int l = tid; l < LONGN; l += 256) scores[l] *= inv;
  }
  __syncthreads();

  for (int l = tid; l < 1024; l += 256) {
    if (l < LONGN) {
      unsigned vb = __float_as_uint(scores[l]);
      kv[l] = ((unsigned long long)(~vb) << 32) | (unsigned)l;
    } else {
      kv[l] = 0xFFFFFFFFFFFFFFFFull;
    }
  }
  __syncthreads();

  for (int k = 2; k <= 1024; k <<= 1) {
    for (int j = k >> 1; j > 0; j >>= 1) {
      #pragma unroll 2
      for (int p = tid; p < 512; p += 256) {
        const int i = ((p & ~(j-1)) << 1) | (p & (j-1));
        const int m = i + j;
        const bool up = ((i & k) == 0);
        unsigned long long a = kv[i], c = kv[m];
        if ((a > c) == up) { kv[i] = c; kv[m] = a; }
      }
      __syncthreads();
    }
  }

  if (tid < TOPKN) {
    unsigned long long key = kv[tid];
    selI[tid] = (int)(unsigned)(key & 0xFFFFFFFFu);
    selV[tid] = __uint_as_float(~(unsigned)(key >> 32));
  }
  __syncthreads();

  if (wid == 0) {
    float v = (lane < TOPKN) ? selV[lane] : -INFINITY;
    float m2 = wave_max(v);
    float e = (lane < TOPKN) ? expf(v - m2) : 0.f;
    float s2 = wave_sum(e);
    if (lane < TOPKN) selV[lane] = e / s2;
  }
  __syncthreads();

  float accR = 0.f;
  for (int r = wid; r < TOPKN; r += 4)
    accR += selV[r] * item_emb[idsL[selI[r]]*64 + lane];
  redE[wid*64 + lane] = accR;
  __syncthreads();
  if (wid == 0)
    comb[64 + lane] = redE[lane] + redE[64+lane] + redE[128+lane] + redE[192+lane];
  __syncthreads();

  h1[tid] = fmaxf(b1[tid] + dotN<256>(w1 + tid*256, comb), 0.f);
  __syncthreads();
  if (tid < 128) h2[tid] = fmaxf(b2[tid] + dotN<256>(w2 + tid*256, h1), 0.f);
  __syncthreads();
  if (tid < 64) {
    float p = w3[tid]*h2[tid] + w3[tid+64]*h2[tid+64];
    p = wave_sum(p);
    if (tid == 0) out[b] = p + b3[0];
  }
}

extern "C" void kernel_launch(void* const* d_in, const int* in_sizes, int n_in,
                              void* d_out, int out_size, void* d_ws, size_t ws_size,
                              hipStream_t stream) {
  const float* user_features  = (const float*)d_in[0];
  const int*   target_item_id = (const int*)  d_in[1];
  const int*   short_hist_ids = (const int*)  d_in[2];
  const int*   long_hist_ids  = (const int*)  d_in[3];
  const float* item_emb       = (const float*)d_in[4];
  const float* tproj_w  = (const float*)d_in[5];
  const float* tproj_b  = (const float*)d_in[6];
  const float* attn_w1  = (const float*)d_in[7];
  const float* attn_b1  = (const float*)d_in[8];
  const float* attn_w2  = (const float*)d_in[9];
  const float* attn_b2  = (const float*)d_in[10];
  const float* hash_emb = (const float*)d_in[11];
  const float* sdim_w   = (const float*)d_in[12];
  const float* sdim_b   = (const float*)d_in[13];
  const float* tf_qkv_w = (const float*)d_in[14];
  const float* tf_qkv_b = (const float*)d_in[15];
  const float* tf_out_w = (const float*)d_in[16];
  const float* tf_out_b = (const float*)d_in[17];
  const float* tf_ln1_g = (const float*)d_in[18];
  const float* tf_ln1_b = (const float*)d_in[19];
  const float* tf_ff1_w = (const float*)d_in[20];
  const float* tf_ff1_b = (const float*)d_in[21];
  const float* tf_ff2_w = (const float*)d_in[22];
  const float* tf_ff2_b = (const float*)d_in[23];
  const float* tf_ln2_g = (const float*)d_in[24];
  const float* tf_ln2_b = (const float*)d_in[25];
  const float* fus_w1   = (const float*)d_in[26];
  const float* fus_b1   = (const float*)d_in[27];
  const float* fus_w2   = (const float*)d_in[28];
  const float* fus_b2   = (const float*)d_in[29];
  const float* fus_w3   = (const float*)d_in[30];
  const float* fus_b3   = (const float*)d_in[31];

  float* ws = (float*)d_ws;
  float* hard = ws;                    // NB*64 (unused, kept for layout)
  float* soft = hard + NB*64;          // NB*64 (unused)
  float* bst  = soft + NB*64;          // NB*64
  float* scores_ws = bst + NB*64;      // NB*1000
  float* partA = scores_ws + NB*LONGN; // NB*2*64
  float* partH = partA + NB*2*64;      // NB*2*64
  short* wF    = (short*)(partH + NB*2*64); // 65536 shorts (128 KB)

  bst_prep_kernel<<<32, 256, 0, stream>>>(tf_qkv_w, tf_out_w, tf_ff1_w, tf_ff2_w, wF);
  hard_scores_kernel<<<2*NB, 256, 0, stream>>>(target_item_id, long_hist_ids,
      item_emb, tproj_w, tproj_b, attn_w1, attn_b1, attn_w2, attn_b2,
      hash_emb, scores_ws, partA, partH);
  bst_kernel<<<NB, 256, 0, stream>>>(short_hist_ids, item_emb, wF,
      tf_qkv_b, tf_out_b, tf_ln1_g, tf_ln1_b, tf_ff1_b, tf_ff2_b,
      tf_ln2_g, tf_ln2_b, bst);
  hard_finish_fusion_kernel<<<NB, 256, 0, stream>>>(long_hist_ids, item_emb,
      sdim_w, sdim_b, scores_ws, partA, partH,
      user_features, bst, fus_w1, fus_b1, fus_w2, fus_b2, fus_w3, fus_b3,
      (float*)d_out);
}

// Round 14
// 165.204 us; speedup vs baseline: 1.3803x; 1.3803x over previous
//
#include <hip/hip_runtime.h>
#include <math.h>

#define NB 512
#define LONGN 1000
#define SHORTN 50
#define TOPKN 50
#define HALFN 500
#define NG 8          // item-groups per hard block
#define EROW 72       // hard-path bf16 LDS row stride (shorts)
#define BROW 72       // bst bf16 row stride (shorts) for xbf/obf
#define F1ROW 136     // bst bf16 row stride for ff1 output (128+8)

typedef __attribute__((ext_vector_type(8))) short bf16x8;
typedef __attribute__((ext_vector_type(4))) float f32x4;

__device__ __forceinline__ float dot4(float4 a, float4 b) {
  return a.x*b.x + a.y*b.y + a.z*b.z + a.w*b.w;
}

template<int N>
__device__ __forceinline__ float dotN(const float* w, const float* x) {
  const float4* w4 = (const float4*)w;
  const float4* x4 = (const float4*)x;
  float a0 = 0.f, a1 = 0.f, a2 = 0.f, a3 = 0.f;
  #pragma unroll
  for (int k = 0; k < N/4; k += 4) {
    a0 += dot4(w4[k],   x4[k]);
    a1 += dot4(w4[k+1], x4[k+1]);
    a2 += dot4(w4[k+2], x4[k+2]);
    a3 += dot4(w4[k+3], x4[k+3]);
  }
  return (a0 + a1) + (a2 + a3);
}

__device__ __forceinline__ float wave_sum(float v) {
  #pragma unroll
  for (int off = 32; off > 0; off >>= 1) v += __shfl_xor(v, off);
  return v;
}
__device__ __forceinline__ float wave_max(float v) {
  #pragma unroll
  for (int off = 32; off > 0; off >>= 1) v = fmaxf(v, __shfl_xor(v, off));
  return v;
}

__device__ __forceinline__ unsigned short f2bf(float x) {  // RNE fp32->bf16
  unsigned u = __float_as_uint(x);
  return (unsigned short)((u + 0x7fffu + ((u >> 16) & 1u)) >> 16);
}

// ===========================================================================
// K1 (MFMA): hard-search scores. (unchanged from R12)
// ===========================================================================
__global__ __launch_bounds__(256, 3) void hard_scores_kernel(
    const int* __restrict__ target_item_id,
    const int* __restrict__ long_hist_ids,
    const float* __restrict__ item_emb,
    const float* __restrict__ tproj_w, const float* __restrict__ tproj_b,
    const float* __restrict__ attn_w1, const float* __restrict__ attn_b1,
    const float* __restrict__ attn_w2, const float* __restrict__ attn_b2,
    const float* __restrict__ hash_emb,
    float* __restrict__ scores_ws, float* __restrict__ partA,
    float* __restrict__ partH)
{
  __shared__ __align__(16) short Abf[64*EROW];
  __shared__ __align__(16) short Ebuf[2][64*EROW];
  __shared__ __align__(16) float tv[64];
  __shared__ __align__(16) float te[64];
  __shared__ __align__(16) float2 cw[64];
  __shared__ int idsL[HALFN];
  __shared__ __align__(16) float redE[4*64];

  const int bid = blockIdx.x;
  const int b = bid >> 1, half = bid & 1;
  const int base = half * HALFN;
  const int tid = threadIdx.x;
  const int wid = tid >> 6, lane = tid & 63;

  if (tid < 64) tv[tid] = item_emb[target_item_id[b]*64 + tid];
  for (int l = tid; l < HALFN; l += 256) idsL[l] = long_hist_ids[b*LONGN + base + l];
  __syncthreads();
  if (tid < 64) te[tid] = tproj_b[tid] + dotN<64>(tproj_w + tid*64, tv);
  __syncthreads();
  if (tid < 64) {
    float c = attn_b1[tid] + dotN<64>(attn_w1 + tid*192, te);
    cw[tid] = make_float2(c, attn_w2[tid]);
  }
  for (int idx = tid; idx < 4096; idx += 256) {
    int i = idx >> 6, j = idx & 63;
    Abf[i*EROW + j] = (short)f2bf(attn_w1[i*192 + 64 + j] + attn_w1[i*192 + 128 + j]*te[j]);
  }
  __syncthreads();

  bf16x8 a00,a01,a10,a11,a20,a21,a30,a31;
  {
    const short* ap = Abf + (lane & 15)*EROW + ((lane >> 4) << 3);
    a00 = *(const bf16x8*)(ap +  0*EROW);  a01 = *(const bf16x8*)(ap +  0*EROW + 32);
    a10 = *(const bf16x8*)(ap + 16*EROW);  a11 = *(const bf16x8*)(ap + 16*EROW + 32);
    a20 = *(const bf16x8*)(ap + 32*EROW);  a21 = *(const bf16x8*)(ap + 32*EROW + 32);
    a30 = *(const bf16x8*)(ap + 48*EROW);  a31 = *(const bf16x8*)(ap + 48*EROW + 32);
  }

  const float b2s = attn_b2[0];
  const int it_g = tid >> 2;
  const int dimg = (tid & 3) * 16;

  float4 sE0 = {0,0,0,0}, sE1 = {0,0,0,0}, sE2 = {0,0,0,0}, sE3 = {0,0,0,0};

  {
    const float4* ep = (const float4*)(item_emb + (size_t)idsL[it_g]*64 + dimg);
    float4 r0 = ep[0], r1 = ep[1], r2 = ep[2], r3 = ep[3];
    sE0.x+=r0.x; sE0.y+=r0.y; sE0.z+=r0.z; sE0.w+=r0.w;
    sE1.x+=r1.x; sE1.y+=r1.y; sE1.z+=r1.z; sE1.w+=r1.w;
    sE2.x+=r2.x; sE2.y+=r2.y; sE2.z+=r2.z; sE2.w+=r2.w;
    sE3.x+=r3.x; sE3.y+=r3.y; sE3.z+=r3.z; sE3.w+=r3.w;
    bf16x8 w0, w1;
    w0[0]=(short)f2bf(r0.x); w0[1]=(short)f2bf(r0.y); w0[2]=(short)f2bf(r0.z); w0[3]=(short)f2bf(r0.w);
    w0[4]=(short)f2bf(r1.x); w0[5]=(short)f2bf(r1.y); w0[6]=(short)f2bf(r1.z); w0[7]=(short)f2bf(r1.w);
    w1[0]=(short)f2bf(r2.x); w1[1]=(short)f2bf(r2.y); w1[2]=(short)f2bf(r2.z); w1[3]=(short)f2bf(r2.w);
    w1[4]=(short)f2bf(r3.x); w1[5]=(short)f2bf(r3.y); w1[6]=(short)f2bf(r3.z); w1[7]=(short)f2bf(r3.w);
    short* dst = &Ebuf[0][it_g*EROW + dimg];
    *(bf16x8*)dst = w0;  *(bf16x8*)(dst + 8) = w1;
  }
  __syncthreads();

  int buf = 0;
  for (int g = 0; g < NG; ++g) {
    float4 r0={0,0,0,0}, r1={0,0,0,0}, r2={0,0,0,0}, r3={0,0,0,0};
    const bool more = (g + 1 < NG);
    if (more) {
      const int gi = (g+1)*64 + it_g;
      if (gi < HALFN) {
        const float4* ep = (const float4*)(item_emb + (size_t)idsL[gi]*64 + dimg);
        r0 = ep[0]; r1 = ep[1]; r2 = ep[2]; r3 = ep[3];
      }
    }

    f32x4 acc0={0,0,0,0}, acc1={0,0,0,0}, acc2={0,0,0,0}, acc3={0,0,0,0};
    {
      const short* ep = &Ebuf[buf][(wid*16 + (lane & 15))*EROW + ((lane >> 4) << 3)];
      bf16x8 b0 = *(const bf16x8*)(ep);
      bf16x8 b1 = *(const bf16x8*)(ep + 32);
      acc0 = __builtin_amdgcn_mfma_f32_16x16x32_bf16(a00, b0, acc0, 0, 0, 0);
      acc0 = __builtin_amdgcn_mfma_f32_16x16x32_bf16(a01, b1, acc0, 0, 0, 0);
      acc1 = __builtin_amdgcn_mfma_f32_16x16x32_bf16(a10, b0, acc1, 0, 0, 0);
      acc1 = __builtin_amdgcn_mfma_f32_16x16x32_bf16(a11, b1, acc1, 0, 0, 0);
      acc2 = __builtin_amdgcn_mfma_f32_16x16x32_bf16(a20, b0, acc2, 0, 0, 0);
      acc2 = __builtin_amdgcn_mfma_f32_16x16x32_bf16(a21, b1, acc2, 0, 0, 0);
      acc3 = __builtin_amdgcn_mfma_f32_16x16x32_bf16(a30, b0, acc3, 0, 0, 0);
      acc3 = __builtin_amdgcn_mfma_f32_16x16x32_bf16(a31, b1, acc3, 0, 0, 0);
    }
    float p = 0.f;
    {
      const int rbase = (lane >> 4) << 2;
      #pragma unroll
      for (int r = 0; r < 4; ++r) {
        float2 c0 = cw[ 0 + rbase + r];
        float2 c1 = cw[16 + rbase + r];
        float2 c2 = cw[32 + rbase + r];
        float2 c3 = cw[48 + rbase + r];
        p += c0.y * fmaxf(acc0[r] + c0.x, 0.f);
        p += c1.y * fmaxf(acc1[r] + c1.x, 0.f);
        p += c2.y * fmaxf(acc2[r] + c2.x, 0.f);
        p += c3.y * fmaxf(acc3[r] + c3.x, 0.f);
      }
    }
    p += __shfl_xor(p, 16);
    p += __shfl_xor(p, 32);
    if (lane < 16) {
      const int gi = g*64 + wid*16 + lane;
      if (gi < HALFN) scores_ws[b*LONGN + base + gi] = b2s + p;
    }

    if (more) {
      sE0.x+=r0.x; sE0.y+=r0.y; sE0.z+=r0.z; sE0.w+=r0.w;
      sE1.x+=r1.x; sE1.y+=r1.y; sE1.z+=r1.z; sE1.w+=r1.w;
      sE2.x+=r2.x; sE2.y+=r2.y; sE2.z+=r2.z; sE2.w+=r2.w;
      sE3.x+=r3.x; sE3.y+=r3.y; sE3.z+=r3.z; sE3.w+=r3.w;
      bf16x8 w0, w1;
      w0[0]=(short)f2bf(r0.x); w0[1]=(short)f2bf(r0.y); w0[2]=(short)f2bf(r0.z); w0[3]=(short)f2bf(r0.w);
      w0[4]=(short)f2bf(r1.x); w0[5]=(short)f2bf(r1.y); w0[6]=(short)f2bf(r1.z); w0[7]=(short)f2bf(r1.w);
      w1[0]=(short)f2bf(r2.x); w1[1]=(short)f2bf(r2.y); w1[2]=(short)f2bf(r2.z); w1[3]=(short)f2bf(r2.w);
      w1[4]=(short)f2bf(r3.x); w1[5]=(short)f2bf(r3.y); w1[6]=(short)f2bf(r3.z); w1[7]=(short)f2bf(r3.w);
      short* dst = &Ebuf[buf ^ 1][it_g*EROW + dimg];
      *(bf16x8*)dst = w0;  *(bf16x8*)(dst + 8) = w1;
    }
    __syncthreads();
    buf ^= 1;
  }

  {
    float* red = (float*)&Ebuf[0][0];
    const int b17 = tid * 17;
    red[b17+ 0]=sE0.x; red[b17+ 1]=sE0.y; red[b17+ 2]=sE0.z; red[b17+ 3]=sE0.w;
    red[b17+ 4]=sE1.x; red[b17+ 5]=sE1.y; red[b17+ 6]=sE1.z; red[b17+ 7]=sE1.w;
    red[b17+ 8]=sE2.x; red[b17+ 9]=sE2.y; red[b17+10]=sE2.z; red[b17+11]=sE2.w;
    red[b17+12]=sE3.x; red[b17+13]=sE3.y; red[b17+14]=sE3.z; red[b17+15]=sE3.w;
    __syncthreads();
    if (tid < 64) {
      const int dg = tid >> 4, dw = tid & 15;
      float s = 0.f;
      for (int j = 0; j < 64; ++j) s += red[(j*4 + dg)*17 + dw];
      partA[bid*64 + tid] = s;
    }
  }

  {
    const int hl = lane >> 4, dd = lane & 15;
    const float* hb = hash_emb + hl*1024*16 + dd;
    float accH = 0.f;
    for (int l = wid; l < HALFN; l += 4)
      accH += hb[(idsL[l] & 1023)*16];
    redE[wid*64 + lane] = accH;
  }
  __syncthreads();
  if (wid == 0)
    partH[bid*64 + lane] = redE[lane] + redE[64+lane] + redE[128+lane] + redE[192+lane];
}

// ===========================================================================
// BST weight prep (unchanged).
// ===========================================================================
__global__ __launch_bounds__(256) void bst_prep_kernel(
    const float* __restrict__ qkv_w, const float* __restrict__ out_w,
    const float* __restrict__ ff1_w, const float* __restrict__ ff2_w,
    short* __restrict__ wF)
{
  const int t = blockIdx.x*256 + threadIdx.x;   // 8192 threads
  if (t >= 8192) return;
  const int fid = t >> 6, lane = t & 63;
  const int n16 = lane & 15, k8 = (lane >> 4) * 8;
  const float* src;
  if (fid < 48)      { int f=fid,    l=f/24, r=f%24, nt=r>>1, kc=r&1;
    src = qkv_w + l*12288 + (nt*16+n16)*64 + kc*32 + k8; }
  else if (fid < 64) { int f=fid-48, l=f>>3, r=f&7,  nt=r>>1, kc=r&1;
    src = out_w + l*4096 + (nt*16+n16)*64 + kc*32 + k8; }
  else if (fid < 96) { int f=fid-64, l=f>>4, r=f&15, nt=r>>1, kc=r&1;
    src = ff1_w + l*8192 + (nt*16+n16)*64 + kc*32 + k8; }
  else               { int f=fid-96, l=f>>4, r=f&15, nt=r>>2, kc=r&3;
    src = ff2_w + l*8192 + (nt*16+n16)*128 + kc*32 + k8; }
  short* dst = wF + fid*512 + lane*8;
  #pragma unroll
  for (int j = 0; j < 8; ++j) dst[j] = (short)f2bf(src[j]);
}

// ===========================================================================
// BST transformer v9: 512 threads, __launch_bounds__(512,2) (VGPR cap 128 >=
// measured 112). GEMM phases split M across wave pairs: wave w = (mh=w&1
// owning m-tiles {2mh,2mh+1}, wg=w>>1 owning n-tiles) -> 16 waves/CU in all
// MFMA/LN phases (2x R12). Attention identical to R12 (tid<200).
// ===========================================================================
__global__ __launch_bounds__(512, 2) void bst_kernel(
    const int* __restrict__ short_ids, const float* __restrict__ item_emb,
    const short* __restrict__ wF,
    const float* __restrict__ qkv_b, const float* __restrict__ out_b,
    const float* __restrict__ ln1_g, const float* __restrict__ ln1_b,
    const float* __restrict__ ff1_b, const float* __restrict__ ff2_b,
    const float* __restrict__ ln2_g, const float* __restrict__ ln2_b,
    float* __restrict__ bst_out)
{
  __shared__ __align__(16) float xf[SHORTN*64];
  __shared__ __align__(16) short xbf[64*BROW];
  __shared__ __align__(16) float qf[SHORTN*68];
  __shared__ __align__(16) float arena[SHORTN*132];
  __shared__ __align__(16) short obf[64*BROW];

  short* f1bf = (short*)arena;

  const int b = blockIdx.x, tid = threadIdx.x;
  const int w8 = tid >> 6, lane = tid & 63;
  const int mh = w8 & 1, wg = w8 >> 1;        // m-half, n-group
  const int n16 = lane & 15;
  const int kg8 = (lane >> 4) << 3;
  const int mrow = (lane >> 4) << 2;
  const int rb = 32*mh;                       // row base for this wave's m-half

  for (int idx = tid; idx < SHORTN*64; idx += 512) {
    int s = idx >> 6, j = idx & 63;
    float v = item_emb[short_ids[b*SHORTN + s]*64 + j];
    xf[idx] = v;
    xbf[s*BROW + j] = (short)f2bf(v);
  }
  for (int idx = tid; idx < 14*BROW; idx += 512) {
    xbf[50*BROW + idx] = 0;
    obf[50*BROW + idx] = 0;
  }
  __syncthreads();

  for (int l = 0; l < 2; ++l) {
    // ======== qkv: wave handles 3 n-tiles x 2 m-tiles ========
    {
      const short* ap = xbf + (rb + n16)*BROW + kg8;
      bf16x8 A00 = *(const bf16x8*)(ap);            bf16x8 A01 = *(const bf16x8*)(ap + 32);
      bf16x8 A10 = *(const bf16x8*)(ap + 16*BROW);  bf16x8 A11 = *(const bf16x8*)(ap + 16*BROW + 32);
      #pragma unroll
      for (int t = 0; t < 3; ++t) {
        const int nt = wg*3 + t;
        const short* bp = wF + (size_t)(l*24 + nt*2)*512 + lane*8;
        bf16x8 B0 = *(const bf16x8*)(bp);
        bf16x8 B1 = *(const bf16x8*)(bp + 512);
        f32x4 c0={0,0,0,0}, c1={0,0,0,0};
        c0 = __builtin_amdgcn_mfma_f32_16x16x32_bf16(A00, B0, c0, 0,0,0);
        c0 = __builtin_amdgcn_mfma_f32_16x16x32_bf16(A01, B1, c0, 0,0,0);
        c1 = __builtin_amdgcn_mfma_f32_16x16x32_bf16(A10, B0, c1, 0,0,0);
        c1 = __builtin_amdgcn_mfma_f32_16x16x32_bf16(A11, B1, c1, 0,0,0);
        const int c = nt*16 + n16;
        const float bias = qkv_b[l*192 + c];
        #pragma unroll
        for (int r = 0; r < 4; ++r) {
          const int r0 = rb + mrow + r;       // always < 50 (max 47)
          const int r1 = r0 + 16;
          float v0 = c0[r] + bias;
          float v1 = c1[r] + bias;
          if (c < 64) {
            qf[r0*68 + c] = v0;
            if (r1 < SHORTN) qf[r1*68 + c] = v1;
          } else {
            const int cc = c - 64;
            arena[r0*132 + cc] = v0;
            if (r1 < SHORTN) arena[r1*132 + cc] = v1;
          }
        }
      }
    }
    __syncthreads();

    // ======== attention: f32 online softmax (tid<200, identical to R12) ====
    if (tid < 4*SHORTN) {
      const int h = tid / SHORTN, s = tid - h*SHORTN;
      const float4* qp = (const float4*)(qf + s*68 + h*16);
      const float4 qA = qp[0], qB2 = qp[1], qC = qp[2], qD = qp[3];
      float m = -INFINITY, ss = 0.f;
      float4 oa0 = {0,0,0,0}, oa1 = {0,0,0,0}, oa2 = {0,0,0,0}, oa3 = {0,0,0,0};
      for (int t2 = 0; t2 < SHORTN; ++t2) {
        const float4* kp = (const float4*)(arena + t2*132 + h*16);
        float d = dot4(qA,kp[0]) + dot4(qB2,kp[1]) + dot4(qC,kp[2]) + dot4(qD,kp[3]);
        d *= 0.25f;
        float mn = fmaxf(m, d);
        float al = __expf(m - mn);
        float a  = __expf(d - mn);
        m = mn;
        ss = ss*al + a;
        const float4* vp = (const float4*)(arena + t2*132 + 64 + h*16);
        float4 v0 = vp[0], v1 = vp[1], v2 = vp[2], v3 = vp[3];
        oa0.x = oa0.x*al + a*v0.x; oa0.y = oa0.y*al + a*v0.y;
        oa0.z = oa0.z*al + a*v0.z; oa0.w = oa0.w*al + a*v0.w;
        oa1.x = oa1.x*al + a*v1.x; oa1.y = oa1.y*al + a*v1.y;
        oa1.z = oa1.z*al + a*v1.z; oa1.w = oa1.w*al + a*v1.w;
        oa2.x = oa2.x*al + a*v2.x; oa2.y = oa2.y*al + a*v2.y;
        oa2.z = oa2.z*al + a*v2.z; oa2.w = oa2.w*al + a*v2.w;
        oa3.x = oa3.x*al + a*v3.x; oa3.y = oa3.y*al + a*v3.y;
        oa3.z = oa3.z*al + a*v3.z; oa3.w = oa3.w*al + a*v3.w;
      }
      const float inv = 1.f/ss;
      bf16x8 w0, w1;
      w0[0]=(short)f2bf(oa0.x*inv); w0[1]=(short)f2bf(oa0.y*inv);
      w0[2]=(short)f2bf(oa0.z*inv); w0[3]=(short)f2bf(oa0.w*inv);
      w0[4]=(short)f2bf(oa1.x*inv); w0[5]=(short)f2bf(oa1.y*inv);
      w0[6]=(short)f2bf(oa1.z*inv); w0[7]=(short)f2bf(oa1.w*inv);
      w1[0]=(short)f2bf(oa2.x*inv); w1[1]=(short)f2bf(oa2.y*inv);
      w1[2]=(short)f2bf(oa2.z*inv); w1[3]=(short)f2bf(oa2.w*inv);
      w1[4]=(short)f2bf(oa3.x*inv); w1[5]=(short)f2bf(oa3.y*inv);
      w1[6]=(short)f2bf(oa3.z*inv); w1[7]=(short)f2bf(oa3.w*inv);
      short* op = obf + s*BROW + h*16;
      *(bf16x8*)op = w0;  *(bf16x8*)(op + 8) = w1;
    }
    __syncthreads();

    // ======== out-proj + y: wave handles 1 n-tile x 2 m-tiles ========
    {
      const short* ap = obf + (rb + n16)*BROW + kg8;
      bf16x8 A00 = *(const bf16x8*)(ap);            bf16x8 A01 = *(const bf16x8*)(ap + 32);
      bf16x8 A10 = *(const bf16x8*)(ap + 16*BROW);  bf16x8 A11 = *(const bf16x8*)(ap + 16*BROW + 32);
      const int nt = wg;
      const short* bp = wF + (size_t)(48 + l*8 + nt*2)*512 + lane*8;
      bf16x8 B0 = *(const bf16x8*)(bp);
      bf16x8 B1 = *(const bf16x8*)(bp + 512);
      f32x4 c0={0,0,0,0}, c1={0,0,0,0};
      c0 = __builtin_amdgcn_mfma_f32_16x16x32_bf16(A00, B0, c0, 0,0,0);
      c0 = __builtin_amdgcn_mfma_f32_16x16x32_bf16(A01, B1, c0, 0,0,0);
      c1 = __builtin_amdgcn_mfma_f32_16x16x32_bf16(A10, B0, c1, 0,0,0);
      c1 = __builtin_amdgcn_mfma_f32_16x16x32_bf16(A11, B1, c1, 0,0,0);
      const int c = nt*16 + n16;
      const float bias = out_b[l*64 + c];
      #pragma unroll
      for (int r = 0; r < 4; ++r) {
        const int r0 = rb + mrow + r;
        const int r1 = r0 + 16;
        arena[r0*68 + c] = xf[r0*64 + c] + bias + c0[r];
        if (r1 < SHORTN) arena[r1*68 + c] = xf[r1*64 + c] + bias + c1[r];
      }
      for (int idx = tid; idx < 14*F1ROW; idx += 512) f1bf[50*F1ROW + idx] = 0;
    }
    __syncthreads();

    // ======== LN1 (8 waves) ========
    {
      const float g = ln1_g[l*64 + lane], bb = ln1_b[l*64 + lane];
      for (int s = w8; s < SHORTN; s += 8) {
        float y = arena[s*68 + lane];
        float mean = wave_sum(y) * (1.f/64.f);
        float dv = y - mean;
        float var = wave_sum(dv*dv) * (1.f/64.f);
        float r = dv / sqrtf(var + 1e-5f) * g + bb;
        xf[s*64 + lane] = r;
        xbf[s*BROW + lane] = (short)f2bf(r);
      }
    }
    __syncthreads();

    // ======== ff1: wave handles 2 n-tiles x 2 m-tiles ========
    {
      const short* ap = xbf + (rb + n16)*BROW + kg8;
      bf16x8 A00 = *(const bf16x8*)(ap);            bf16x8 A01 = *(const bf16x8*)(ap + 32);
      bf16x8 A10 = *(const bf16x8*)(ap + 16*BROW);  bf16x8 A11 = *(const bf16x8*)(ap + 16*BROW + 32);
      #pragma unroll
      for (int t = 0; t < 2; ++t) {
        const int nt = wg*2 + t;
        const short* bp = wF + (size_t)(64 + l*16 + nt*2)*512 + lane*8;
        bf16x8 B0 = *(const bf16x8*)(bp);
        bf16x8 B1 = *(const bf16x8*)(bp + 512);
        f32x4 c0={0,0,0,0}, c1={0,0,0,0};
        c0 = __builtin_amdgcn_mfma_f32_16x16x32_bf16(A00, B0, c0, 0,0,0);
        c0 = __builtin_amdgcn_mfma_f32_16x16x32_bf16(A01, B1, c0, 0,0,0);
        c1 = __builtin_amdgcn_mfma_f32_16x16x32_bf16(A10, B0, c1, 0,0,0);
        c1 = __builtin_amdgcn_mfma_f32_16x16x32_bf16(A11, B1, c1, 0,0,0);
        const int c = nt*16 + n16;
        const float bias = ff1_b[l*128 + c];
        #pragma unroll
        for (int r = 0; r < 4; ++r) {
          const int r0 = rb + mrow + r;
          const int r1 = r0 + 16;
          f1bf[r0*F1ROW + c] = (short)f2bf(fmaxf(c0[r] + bias, 0.f));
          if (r1 < SHORTN) f1bf[r1*F1ROW + c] = (short)f2bf(fmaxf(c1[r] + bias, 0.f));
        }
      }
    }
    __syncthreads();

    // ======== ff2: wave handles 1 n-tile x 2 m-tiles, K=128 ========
    {
      const int nt = wg;
      f32x4 c0={0,0,0,0}, c1={0,0,0,0};
      #pragma unroll
      for (int kc = 0; kc < 4; ++kc) {
        const short* ap = f1bf + (rb + n16)*F1ROW + kc*32 + kg8;
        bf16x8 A0 = *(const bf16x8*)(ap);
        bf16x8 A1 = *(const bf16x8*)(ap + 16*F1ROW);
        const short* bp = wF + (size_t)(96 + l*16 + nt*4 + kc)*512 + lane*8;
        bf16x8 B = *(const bf16x8*)(bp);
        c0 = __builtin_amdgcn_mfma_f32_16x16x32_bf16(A0, B, c0, 0,0,0);
        c1 = __builtin_amdgcn_mfma_f32_16x16x32_bf16(A1, B, c1, 0,0,0);
      }
      __syncthreads();   // all f1bf reads complete before y2 overlays arena
      const int c = nt*16 + n16;
      const float bias = ff2_b[l*64 + c];
      #pragma unroll
      for (int r = 0; r < 4; ++r) {
        const int r0 = rb + mrow + r;
        const int r1 = r0 + 16;
        arena[r0*68 + c] = xf[r0*64 + c] + bias + c0[r];
        if (r1 < SHORTN) arena[r1*68 + c] = xf[r1*64 + c] + bias + c1[r];
      }
    }
    __syncthreads();

    // ======== LN2 (8 waves) ========
    {
      const float g = ln2_g[l*64 + lane], bb = ln2_b[l*64 + lane];
      for (int s = w8; s < SHORTN; s += 8) {
        float y = arena[s*68 + lane];
        float mean = wave_sum(y) * (1.f/64.f);
        float dv = y - mean;
        float var = wave_sum(dv*dv) * (1.f/64.f);
        float r = dv / sqrtf(var + 1e-5f) * g + bb;
        xf[s*64 + lane] = r;
        xbf[s*BROW + lane] = (short)f2bf(r);
      }
    }
    __syncthreads();
  }

  // mean over sequence (8 wave-partials -> reduce)
  float acc = 0.f;
  for (int s = w8; s < SHORTN; s += 8) acc += xf[s*64 + lane];
  qf[w8*64 + lane] = acc;
  __syncthreads();
  if (w8 == 0) {
    float t = qf[lane];
    #pragma unroll
    for (int w = 1; w < 8; ++w) t += qf[w*64 + lane];
    bst_out[b*64 + lane] = t * (1.f/50.f);
  }
}

// ===========================================================================
// K2+K4 merged: softmax(1000) + bitonic top-50 + re-softmax + hard/soft repr
// kept in LDS + fusion MLP -> final out. grid = NB. (unchanged from R12)
// ===========================================================================
__global__ __launch_bounds__(256) void hard_finish_fusion_kernel(
    const int* __restrict__ long_hist_ids,
    const float* __restrict__ item_emb,
    const float* __restrict__ sdim_w, const float* __restrict__ sdim_b,
    const float* __restrict__ scores_ws,
    const float* __restrict__ partA, const float* __restrict__ partH,
    const float* __restrict__ user, const float* __restrict__ bst,
    const float* __restrict__ w1, const float* __restrict__ b1,
    const float* __restrict__ w2, const float* __restrict__ b2,
    const float* __restrict__ w3, const float* __restrict__ b3,
    float* __restrict__ out)
{
  __shared__ __align__(16) float scores[LONGN];
  __shared__ int   idsL[LONGN];
  __shared__ __align__(16) unsigned long long kv[1024];
  __shared__ __align__(16) float redE[4*64];
  __shared__ __align__(16) float vecbuf[64];
  __shared__ float redV[4];
  __shared__ float selV[TOPKN];
  __shared__ int   selI[TOPKN];
  __shared__ __align__(16) float comb[256];
  __shared__ __align__(16) float h1[256];
  __shared__ __align__(16) float h2[128];

  const int b = blockIdx.x;
  const int tid = threadIdx.x;
  const int wid = tid >> 6, lane = tid & 63;

  for (int l = tid; l < LONGN; l += 256) {
    scores[l] = scores_ws[b*LONGN + l];
    idsL[l] = long_hist_ids[b*LONGN + l];
  }
  if (tid < 64)       comb[tid] = user[b*64 + tid];
  else if (tid >= 192) comb[tid] = bst[b*64 + tid - 192];
  __syncthreads();

  if (tid < 64)
    vecbuf[tid] = (partA[(2*b)*64 + tid] + partA[(2*b+1)*64 + tid]
                 + partH[(2*b)*64 + tid] + partH[(2*b+1)*64 + tid]) * (1.f/1000.f);
  __syncthreads();
  if (tid < 64)
    comb[128 + tid] = sdim_b[tid] + dotN<64>(sdim_w + tid*64, vecbuf);

  float mx = -INFINITY;
  for (int l = tid; l < LONGN; l += 256) mx = fmaxf(mx, scores[l]);
  mx = wave_max(mx);
  if (lane == 0) redV[wid] = mx;
  __syncthreads();
  mx = fmaxf(fmaxf(redV[0], redV[1]), fmaxf(redV[2], redV[3]));
  __syncthreads();
  float sm = 0.f;
  for (int l = tid; l < LONGN; l += 256) {
    float a = expf(scores[l] - mx);
    scores[l] = a;
    sm += a;
  }
  sm = wave_sum(sm);
  if (lane == 0) redV[wid] = sm;
  __syncthreads();
  {
    const float inv = 1.f / (redV[0] + redV[1] + redV[2] + redV[3]);
    for (int l = tid; l < LONGN; l += 256) scores[l] *= inv;
  }
  __syncthreads();

  for (int l = tid; l < 1024; l += 256) {
    if (l < LONGN) {
      unsigned vb = __float_as_uint(scores[l]);
      kv[l] = ((unsigned long long)(~vb) << 32) | (unsigned)l;
    } else {
      kv[l] = 0xFFFFFFFFFFFFFFFFull;
    }
  }
  __syncthreads();

  for (int k = 2; k <= 1024; k <<= 1) {
    for (int j = k >> 1; j > 0; j >>= 1) {
      #pragma unroll 2
      for (int p = tid; p < 512; p += 256) {
        const int i = ((p & ~(j-1)) << 1) | (p & (j-1));
        const int m = i + j;
        const bool up = ((i & k) == 0);
        unsigned long long a = kv[i], c = kv[m];
        if ((a > c) == up) { kv[i] = c; kv[m] = a; }
      }
      __syncthreads();
    }
  }

  if (tid < TOPKN) {
    unsigned long long key = kv[tid];
    selI[tid] = (int)(unsigned)(key & 0xFFFFFFFFu);
    selV[tid] = __uint_as_float(~(unsigned)(key >> 32));
  }
  __syncthreads();

  if (wid == 0) {
    float v = (lane < TOPKN) ? selV[lane] : -INFINITY;
    float m2 = wave_max(v);
    float e = (lane < TOPKN) ? expf(v - m2) : 0.f;
    float s2 = wave_sum(e);
    if (lane < TOPKN) selV[lane] = e / s2;
  }
  __syncthreads();

  float accR = 0.f;
  for (int r = wid; r < TOPKN; r += 4)
    accR += selV[r] * item_emb[idsL[selI[r]]*64 + lane];
  redE[wid*64 + lane] = accR;
  __syncthreads();
  if (wid == 0)
    comb[64 + lane] = redE[lane] + redE[64+lane] + redE[128+lane] + redE[192+lane];
  __syncthreads();

  h1[tid] = fmaxf(b1[tid] + dotN<256>(w1 + tid*256, comb), 0.f);
  __syncthreads();
  if (tid < 128) h2[tid] = fmaxf(b2[tid] + dotN<256>(w2 + tid*256, h1), 0.f);
  __syncthreads();
  if (tid < 64) {
    float p = w3[tid]*h2[tid] + w3[tid+64]*h2[tid+64];
    p = wave_sum(p);
    if (tid == 0) out[b] = p + b3[0];
  }
}

extern "C" void kernel_launch(void* const* d_in, const int* in_sizes, int n_in,
                              void* d_out, int out_size, void* d_ws, size_t ws_size,
                              hipStream_t stream) {
  const float* user_features  = (const float*)d_in[0];
  const int*   target_item_id = (const int*)  d_in[1];
  const int*   short_hist_ids = (const int*)  d_in[2];
  const int*   long_hist_ids  = (const int*)  d_in[3];
  const float* item_emb       = (const float*)d_in[4];
  const float* tproj_w  = (const float*)d_in[5];
  const float* tproj_b  = (const float*)d_in[6];
  const float* attn_w1  = (const float*)d_in[7];
  const float* attn_b1  = (const float*)d_in[8];
  const float* attn_w2  = (const float*)d_in[9];
  const float* attn_b2  = (const float*)d_in[10];
  const float* hash_emb = (const float*)d_in[11];
  const float* sdim_w   = (const float*)d_in[12];
  const float* sdim_b   = (const float*)d_in[13];
  const float* tf_qkv_w = (const float*)d_in[14];
  const float* tf_qkv_b = (const float*)d_in[15];
  const float* tf_out_w = (const float*)d_in[16];
  const float* tf_out_b = (const float*)d_in[17];
  const float* tf_ln1_g = (const float*)d_in[18];
  const float* tf_ln1_b = (const float*)d_in[19];
  const float* tf_ff1_w = (const float*)d_in[20];
  const float* tf_ff1_b = (const float*)d_in[21];
  const float* tf_ff2_w = (const float*)d_in[22];
  const float* tf_ff2_b = (const float*)d_in[23];
  const float* tf_ln2_g = (const float*)d_in[24];
  const float* tf_ln2_b = (const float*)d_in[25];
  const float* fus_w1   = (const float*)d_in[26];
  const float* fus_b1   = (const float*)d_in[27];
  const float* fus_w2   = (const float*)d_in[28];
  const float* fus_b2   = (const float*)d_in[29];
  const float* fus_w3   = (const float*)d_in[30];
  const float* fus_b3   = (const float*)d_in[31];

  float* ws = (float*)d_ws;
  float* hard = ws;                    // NB*64 (unused, kept for layout)
  float* soft = hard + NB*64;          // NB*64 (unused)
  float* bst  = soft + NB*64;          // NB*64
  float* scores_ws = bst + NB*64;      // NB*1000
  float* partA = scores_ws + NB*LONGN; // NB*2*64
  float* partH = partA + NB*2*64;      // NB*2*64
  short* wF    = (short*)(partH + NB*2*64); // 65536 shorts (128 KB)

  bst_prep_kernel<<<32, 256, 0, stream>>>(tf_qkv_w, tf_out_w, tf_ff1_w, tf_ff2_w, wF);
  hard_scores_kernel<<<2*NB, 256, 0, stream>>>(target_item_id, long_hist_ids,
      item_emb, tproj_w, tproj_b, attn_w1, attn_b1, attn_w2, attn_b2,
      hash_emb, scores_ws, partA, partH);
  bst_kernel<<<NB, 512, 0, stream>>>(short_hist_ids, item_emb, wF,
      tf_qkv_b, tf_out_b, tf_ln1_g, tf_ln1_b, tf_ff1_b, tf_ff2_b,
      tf_ln2_g, tf_ln2_b, bst);
  hard_finish_fusion_kernel<<<NB, 256, 0, stream>>>(long_hist_ids, item_emb,
      sdim_w, sdim_b, scores_ws, partA, partH,
      user_features, bst, fus_w1, fus_b1, fus_w2, fus_b2, fus_w3, fus_b3,
      (float*)d_out);
}

// Round 15
// 141.509 us; speedup vs baseline: 1.6115x; 1.1674x over previous
//
#include <hip/hip_runtime.h>
#include <math.h>

#define NB 512
#define LONGN 1000
#define SHORTN 50
#define TOPKN 50
#define HALFN 500
#define NG 8          // item-groups per hard block
#define EROW 72       // hard-path bf16 LDS row stride (shorts)
#define BROW 72       // bst bf16 row stride (shorts) for xbf/obf
#define F1ROW 136     // bst bf16 row stride for ff1 output (128+8)

typedef __attribute__((ext_vector_type(8))) short bf16x8;
typedef __attribute__((ext_vector_type(4))) float f32x4;

__device__ __forceinline__ float dot4(float4 a, float4 b) {
  return a.x*b.x + a.y*b.y + a.z*b.z + a.w*b.w;
}

template<int N>
__device__ __forceinline__ float dotN(const float* w, const float* x) {
  const float4* w4 = (const float4*)w;
  const float4* x4 = (const float4*)x;
  float a0 = 0.f, a1 = 0.f, a2 = 0.f, a3 = 0.f;
  #pragma unroll
  for (int k = 0; k < N/4; k += 4) {
    a0 += dot4(w4[k],   x4[k]);
    a1 += dot4(w4[k+1], x4[k+1]);
    a2 += dot4(w4[k+2], x4[k+2]);
    a3 += dot4(w4[k+3], x4[k+3]);
  }
  return (a0 + a1) + (a2 + a3);
}

__device__ __forceinline__ float wave_sum(float v) {
  #pragma unroll
  for (int off = 32; off > 0; off >>= 1) v += __shfl_xor(v, off);
  return v;
}
__device__ __forceinline__ float wave_max(float v) {
  #pragma unroll
  for (int off = 32; off > 0; off >>= 1) v = fmaxf(v, __shfl_xor(v, off));
  return v;
}

__device__ __forceinline__ unsigned short f2bf(float x) {  // RNE fp32->bf16
  unsigned u = __float_as_uint(x);
  return (unsigned short)((u + 0x7fffu + ((u >> 16) & 1u)) >> 16);
}

// ===========================================================================
// K1 (MFMA): hard-search scores. (R14 + launch_bounds (256,4): whole grid
// co-resident -> more outstanding gathers)
// ===========================================================================
__global__ __launch_bounds__(256, 4) void hard_scores_kernel(
    const int* __restrict__ target_item_id,
    const int* __restrict__ long_hist_ids,
    const float* __restrict__ item_emb,
    const float* __restrict__ tproj_w, const float* __restrict__ tproj_b,
    const float* __restrict__ attn_w1, const float* __restrict__ attn_b1,
    const float* __restrict__ attn_w2, const float* __restrict__ attn_b2,
    const float* __restrict__ hash_emb,
    float* __restrict__ scores_ws, float* __restrict__ partA,
    float* __restrict__ partH)
{
  __shared__ __align__(16) short Abf[64*EROW];
  __shared__ __align__(16) short Ebuf[2][64*EROW];
  __shared__ __align__(16) float tv[64];
  __shared__ __align__(16) float te[64];
  __shared__ __align__(16) float2 cw[64];
  __shared__ int idsL[HALFN];
  __shared__ __align__(16) float redE[4*64];

  const int bid = blockIdx.x;
  const int b = bid >> 1, half = bid & 1;
  const int base = half * HALFN;
  const int tid = threadIdx.x;
  const int wid = tid >> 6, lane = tid & 63;

  if (tid < 64) tv[tid] = item_emb[target_item_id[b]*64 + tid];
  for (int l = tid; l < HALFN; l += 256) idsL[l] = long_hist_ids[b*LONGN + base + l];
  __syncthreads();
  if (tid < 64) te[tid] = tproj_b[tid] + dotN<64>(tproj_w + tid*64, tv);
  __syncthreads();
  if (tid < 64) {
    float c = attn_b1[tid] + dotN<64>(attn_w1 + tid*192, te);
    cw[tid] = make_float2(c, attn_w2[tid]);
  }
  for (int idx = tid; idx < 4096; idx += 256) {
    int i = idx >> 6, j = idx & 63;
    Abf[i*EROW + j] = (short)f2bf(attn_w1[i*192 + 64 + j] + attn_w1[i*192 + 128 + j]*te[j]);
  }
  __syncthreads();

  bf16x8 a00,a01,a10,a11,a20,a21,a30,a31;
  {
    const short* ap = Abf + (lane & 15)*EROW + ((lane >> 4) << 3);
    a00 = *(const bf16x8*)(ap +  0*EROW);  a01 = *(const bf16x8*)(ap +  0*EROW + 32);
    a10 = *(const bf16x8*)(ap + 16*EROW);  a11 = *(const bf16x8*)(ap + 16*EROW + 32);
    a20 = *(const bf16x8*)(ap + 32*EROW);  a21 = *(const bf16x8*)(ap + 32*EROW + 32);
    a30 = *(const bf16x8*)(ap + 48*EROW);  a31 = *(const bf16x8*)(ap + 48*EROW + 32);
  }

  const float b2s = attn_b2[0];
  const int it_g = tid >> 2;
  const int dimg = (tid & 3) * 16;

  float4 sE0 = {0,0,0,0}, sE1 = {0,0,0,0}, sE2 = {0,0,0,0}, sE3 = {0,0,0,0};

  {
    const float4* ep = (const float4*)(item_emb + (size_t)idsL[it_g]*64 + dimg);
    float4 r0 = ep[0], r1 = ep[1], r2 = ep[2], r3 = ep[3];
    sE0.x+=r0.x; sE0.y+=r0.y; sE0.z+=r0.z; sE0.w+=r0.w;
    sE1.x+=r1.x; sE1.y+=r1.y; sE1.z+=r1.z; sE1.w+=r1.w;
    sE2.x+=r2.x; sE2.y+=r2.y; sE2.z+=r2.z; sE2.w+=r2.w;
    sE3.x+=r3.x; sE3.y+=r3.y; sE3.z+=r3.z; sE3.w+=r3.w;
    bf16x8 w0, w1;
    w0[0]=(short)f2bf(r0.x); w0[1]=(short)f2bf(r0.y); w0[2]=(short)f2bf(r0.z); w0[3]=(short)f2bf(r0.w);
    w0[4]=(short)f2bf(r1.x); w0[5]=(short)f2bf(r1.y); w0[6]=(short)f2bf(r1.z); w0[7]=(short)f2bf(r1.w);
    w1[0]=(short)f2bf(r2.x); w1[1]=(short)f2bf(r2.y); w1[2]=(short)f2bf(r2.z); w1[3]=(short)f2bf(r2.w);
    w1[4]=(short)f2bf(r3.x); w1[5]=(short)f2bf(r3.y); w1[6]=(short)f2bf(r3.z); w1[7]=(short)f2bf(r3.w);
    short* dst = &Ebuf[0][it_g*EROW + dimg];
    *(bf16x8*)dst = w0;  *(bf16x8*)(dst + 8) = w1;
  }
  __syncthreads();

  int buf = 0;
  for (int g = 0; g < NG; ++g) {
    float4 r0={0,0,0,0}, r1={0,0,0,0}, r2={0,0,0,0}, r3={0,0,0,0};
    const bool more = (g + 1 < NG);
    if (more) {
      const int gi = (g+1)*64 + it_g;
      if (gi < HALFN) {
        const float4* ep = (const float4*)(item_emb + (size_t)idsL[gi]*64 + dimg);
        r0 = ep[0]; r1 = ep[1]; r2 = ep[2]; r3 = ep[3];
      }
    }

    f32x4 acc0={0,0,0,0}, acc1={0,0,0,0}, acc2={0,0,0,0}, acc3={0,0,0,0};
    {
      const short* ep = &Ebuf[buf][(wid*16 + (lane & 15))*EROW + ((lane >> 4) << 3)];
      bf16x8 b0 = *(const bf16x8*)(ep);
      bf16x8 b1 = *(const bf16x8*)(ep + 32);
      acc0 = __builtin_amdgcn_mfma_f32_16x16x32_bf16(a00, b0, acc0, 0, 0, 0);
      acc0 = __builtin_amdgcn_mfma_f32_16x16x32_bf16(a01, b1, acc0, 0, 0, 0);
      acc1 = __builtin_amdgcn_mfma_f32_16x16x32_bf16(a10, b0, acc1, 0, 0, 0);
      acc1 = __builtin_amdgcn_mfma_f32_16x16x32_bf16(a11, b1, acc1, 0, 0, 0);
      acc2 = __builtin_amdgcn_mfma_f32_16x16x32_bf16(a20, b0, acc2, 0, 0, 0);
      acc2 = __builtin_amdgcn_mfma_f32_16x16x32_bf16(a21, b1, acc2, 0, 0, 0);
      acc3 = __builtin_amdgcn_mfma_f32_16x16x32_bf16(a30, b0, acc3, 0, 0, 0);
      acc3 = __builtin_amdgcn_mfma_f32_16x16x32_bf16(a31, b1, acc3, 0, 0, 0);
    }
    float p = 0.f;
    {
      const int rbase = (lane >> 4) << 2;
      #pragma unroll
      for (int r = 0; r < 4; ++r) {
        float2 c0 = cw[ 0 + rbase + r];
        float2 c1 = cw[16 + rbase + r];
        float2 c2 = cw[32 + rbase + r];
        float2 c3 = cw[48 + rbase + r];
        p += c0.y * fmaxf(acc0[r] + c0.x, 0.f);
        p += c1.y * fmaxf(acc1[r] + c1.x, 0.f);
        p += c2.y * fmaxf(acc2[r] + c2.x, 0.f);
        p += c3.y * fmaxf(acc3[r] + c3.x, 0.f);
      }
    }
    p += __shfl_xor(p, 16);
    p += __shfl_xor(p, 32);
    if (lane < 16) {
      const int gi = g*64 + wid*16 + lane;
      if (gi < HALFN) scores_ws[b*LONGN + base + gi] = b2s + p;
    }

    if (more) {
      sE0.x+=r0.x; sE0.y+=r0.y; sE0.z+=r0.z; sE0.w+=r0.w;
      sE1.x+=r1.x; sE1.y+=r1.y; sE1.z+=r1.z; sE1.w+=r1.w;
      sE2.x+=r2.x; sE2.y+=r2.y; sE2.z+=r2.z; sE2.w+=r2.w;
      sE3.x+=r3.x; sE3.y+=r3.y; sE3.z+=r3.z; sE3.w+=r3.w;
      bf16x8 w0, w1;
      w0[0]=(short)f2bf(r0.x); w0[1]=(short)f2bf(r0.y); w0[2]=(short)f2bf(r0.z); w0[3]=(short)f2bf(r0.w);
      w0[4]=(short)f2bf(r1.x); w0[5]=(short)f2bf(r1.y); w0[6]=(short)f2bf(r1.z); w0[7]=(short)f2bf(r1.w);
      w1[0]=(short)f2bf(r2.x); w1[1]=(short)f2bf(r2.y); w1[2]=(short)f2bf(r2.z); w1[3]=(short)f2bf(r2.w);
      w1[4]=(short)f2bf(r3.x); w1[5]=(short)f2bf(r3.y); w1[6]=(short)f2bf(r3.z); w1[7]=(short)f2bf(r3.w);
      short* dst = &Ebuf[buf ^ 1][it_g*EROW + dimg];
      *(bf16x8*)dst = w0;  *(bf16x8*)(dst + 8) = w1;
    }
    __syncthreads();
    buf ^= 1;
  }

  {
    float* red = (float*)&Ebuf[0][0];
    const int b17 = tid * 17;
    red[b17+ 0]=sE0.x; red[b17+ 1]=sE0.y; red[b17+ 2]=sE0.z; red[b17+ 3]=sE0.w;
    red[b17+ 4]=sE1.x; red[b17+ 5]=sE1.y; red[b17+ 6]=sE1.z; red[b17+ 7]=sE1.w;
    red[b17+ 8]=sE2.x; red[b17+ 9]=sE2.y; red[b17+10]=sE2.z; red[b17+11]=sE2.w;
    red[b17+12]=sE3.x; red[b17+13]=sE3.y; red[b17+14]=sE3.z; red[b17+15]=sE3.w;
    __syncthreads();
    if (tid < 64) {
      const int dg = tid >> 4, dw = tid & 15;
      float s = 0.f;
      for (int j = 0; j < 64; ++j) s += red[(j*4 + dg)*17 + dw];
      partA[bid*64 + tid] = s;
    }
  }

  {
    const int hl = lane >> 4, dd = lane & 15;
    const float* hb = hash_emb + hl*1024*16 + dd;
    float accH = 0.f;
    for (int l = wid; l < HALFN; l += 4)
      accH += hb[(idsL[l] & 1023)*16];
    redE[wid*64 + lane] = accH;
  }
  __syncthreads();
  if (wid == 0)
    partH[bid*64 + lane] = redE[lane] + redE[64+lane] + redE[128+lane] + redE[192+lane];
}

// ===========================================================================
// BST weight prep (unchanged).
// ===========================================================================
__global__ __launch_bounds__(256) void bst_prep_kernel(
    const float* __restrict__ qkv_w, const float* __restrict__ out_w,
    const float* __restrict__ ff1_w, const float* __restrict__ ff2_w,
    short* __restrict__ wF)
{
  const int t = blockIdx.x*256 + threadIdx.x;   // 8192 threads
  if (t >= 8192) return;
  const int fid = t >> 6, lane = t & 63;
  const int n16 = lane & 15, k8 = (lane >> 4) * 8;
  const float* src;
  if (fid < 48)      { int f=fid,    l=f/24, r=f%24, nt=r>>1, kc=r&1;
    src = qkv_w + l*12288 + (nt*16+n16)*64 + kc*32 + k8; }
  else if (fid < 64) { int f=fid-48, l=f>>3, r=f&7,  nt=r>>1, kc=r&1;
    src = out_w + l*4096 + (nt*16+n16)*64 + kc*32 + k8; }
  else if (fid < 96) { int f=fid-64, l=f>>4, r=f&15, nt=r>>1, kc=r&1;
    src = ff1_w + l*8192 + (nt*16+n16)*64 + kc*32 + k8; }
  else               { int f=fid-96, l=f>>4, r=f&15, nt=r>>2, kc=r&3;
    src = ff2_w + l*8192 + (nt*16+n16)*128 + kc*32 + k8; }
  short* dst = wF + fid*512 + lane*8;
  #pragma unroll
  for (int j = 0; j < 8; ++j) dst[j] = (short)f2bf(src[j]);
}

// ===========================================================================
// BST transformer v10: 512 threads (R14 structure) + K-split attention across
// 400 threads (pair shares one (h,s): 25 K-positions each, no-max softmax,
// combine via __shfl_xor(.,1)).
// ===========================================================================
__global__ __launch_bounds__(512, 2) void bst_kernel(
    const int* __restrict__ short_ids, const float* __restrict__ item_emb,
    const short* __restrict__ wF,
    const float* __restrict__ qkv_b, const float* __restrict__ out_b,
    const float* __restrict__ ln1_g, const float* __restrict__ ln1_b,
    const float* __restrict__ ff1_b, const float* __restrict__ ff2_b,
    const float* __restrict__ ln2_g, const float* __restrict__ ln2_b,
    float* __restrict__ bst_out)
{
  __shared__ __align__(16) float xf[SHORTN*64];
  __shared__ __align__(16) short xbf[64*BROW];
  __shared__ __align__(16) float qf[SHORTN*68];
  __shared__ __align__(16) float arena[SHORTN*132];
  __shared__ __align__(16) short obf[64*BROW];

  short* f1bf = (short*)arena;

  const int b = blockIdx.x, tid = threadIdx.x;
  const int w8 = tid >> 6, lane = tid & 63;
  const int mh = w8 & 1, wg = w8 >> 1;        // m-half, n-group
  const int n16 = lane & 15;
  const int kg8 = (lane >> 4) << 3;
  const int mrow = (lane >> 4) << 2;
  const int rb = 32*mh;

  for (int idx = tid; idx < SHORTN*64; idx += 512) {
    int s = idx >> 6, j = idx & 63;
    float v = item_emb[short_ids[b*SHORTN + s]*64 + j];
    xf[idx] = v;
    xbf[s*BROW + j] = (short)f2bf(v);
  }
  for (int idx = tid; idx < 14*BROW; idx += 512) {
    xbf[50*BROW + idx] = 0;
    obf[50*BROW + idx] = 0;
  }
  __syncthreads();

  for (int l = 0; l < 2; ++l) {
    // ======== qkv: wave handles 3 n-tiles x 2 m-tiles ========
    {
      const short* ap = xbf + (rb + n16)*BROW + kg8;
      bf16x8 A00 = *(const bf16x8*)(ap);            bf16x8 A01 = *(const bf16x8*)(ap + 32);
      bf16x8 A10 = *(const bf16x8*)(ap + 16*BROW);  bf16x8 A11 = *(const bf16x8*)(ap + 16*BROW + 32);
      #pragma unroll
      for (int t = 0; t < 3; ++t) {
        const int nt = wg*3 + t;
        const short* bp = wF + (size_t)(l*24 + nt*2)*512 + lane*8;
        bf16x8 B0 = *(const bf16x8*)(bp);
        bf16x8 B1 = *(const bf16x8*)(bp + 512);
        f32x4 c0={0,0,0,0}, c1={0,0,0,0};
        c0 = __builtin_amdgcn_mfma_f32_16x16x32_bf16(A00, B0, c0, 0,0,0);
        c0 = __builtin_amdgcn_mfma_f32_16x16x32_bf16(A01, B1, c0, 0,0,0);
        c1 = __builtin_amdgcn_mfma_f32_16x16x32_bf16(A10, B0, c1, 0,0,0);
        c1 = __builtin_amdgcn_mfma_f32_16x16x32_bf16(A11, B1, c1, 0,0,0);
        const int c = nt*16 + n16;
        const float bias = qkv_b[l*192 + c];
        #pragma unroll
        for (int r = 0; r < 4; ++r) {
          const int r0 = rb + mrow + r;
          const int r1 = r0 + 16;
          float v0 = c0[r] + bias;
          float v1 = c1[r] + bias;
          if (c < 64) {
            qf[r0*68 + c] = v0;
            if (r1 < SHORTN) qf[r1*68 + c] = v1;
          } else {
            const int cc = c - 64;
            arena[r0*132 + cc] = v0;
            if (r1 < SHORTN) arena[r1*132 + cc] = v1;
          }
        }
      }
    }
    __syncthreads();

    // ======== attention: 400 threads, pair-split K (25 positions each),
    //          no-max softmax, pair-combine via shfl_xor(.,1) ========
    if (tid < 8*SHORTN) {
      const int pair = tid >> 1, khalf = tid & 1;
      const int h = pair / SHORTN, s = pair - h*SHORTN;
      const float4* qp = (const float4*)(qf + s*68 + h*16);
      const float4 qA = qp[0], qB2 = qp[1], qC = qp[2], qD = qp[3];
      float ss = 0.f;
      float4 oa0 = {0,0,0,0}, oa1 = {0,0,0,0}, oa2 = {0,0,0,0}, oa3 = {0,0,0,0};
      const int t0 = khalf*25;
      for (int t2 = t0; t2 < t0 + 25; ++t2) {
        const float4* kp = (const float4*)(arena + t2*132 + h*16);
        float d = dot4(qA,kp[0]) + dot4(qB2,kp[1]) + dot4(qC,kp[2]) + dot4(qD,kp[3]);
        float p = __expf(d*0.25f);
        ss += p;
        const float4* vp = (const float4*)(arena + t2*132 + 64 + h*16);
        float4 v0 = vp[0], v1 = vp[1], v2 = vp[2], v3 = vp[3];
        oa0.x += p*v0.x; oa0.y += p*v0.y; oa0.z += p*v0.z; oa0.w += p*v0.w;
        oa1.x += p*v1.x; oa1.y += p*v1.y; oa1.z += p*v1.z; oa1.w += p*v1.w;
        oa2.x += p*v2.x; oa2.y += p*v2.y; oa2.z += p*v2.z; oa2.w += p*v2.w;
        oa3.x += p*v3.x; oa3.y += p*v3.y; oa3.z += p*v3.z; oa3.w += p*v3.w;
      }
      // combine the two K-halves (lanes tid and tid^1 are in the same wave)
      ss    += __shfl_xor(ss, 1);
      oa0.x += __shfl_xor(oa0.x, 1); oa0.y += __shfl_xor(oa0.y, 1);
      oa0.z += __shfl_xor(oa0.z, 1); oa0.w += __shfl_xor(oa0.w, 1);
      oa1.x += __shfl_xor(oa1.x, 1); oa1.y += __shfl_xor(oa1.y, 1);
      oa1.z += __shfl_xor(oa1.z, 1); oa1.w += __shfl_xor(oa1.w, 1);
      oa2.x += __shfl_xor(oa2.x, 1); oa2.y += __shfl_xor(oa2.y, 1);
      oa2.z += __shfl_xor(oa2.z, 1); oa2.w += __shfl_xor(oa2.w, 1);
      oa3.x += __shfl_xor(oa3.x, 1); oa3.y += __shfl_xor(oa3.y, 1);
      oa3.z += __shfl_xor(oa3.z, 1); oa3.w += __shfl_xor(oa3.w, 1);
      if (khalf == 0) {
        const float inv = 1.f/ss;
        bf16x8 w0, w1;
        w0[0]=(short)f2bf(oa0.x*inv); w0[1]=(short)f2bf(oa0.y*inv);
        w0[2]=(short)f2bf(oa0.z*inv); w0[3]=(short)f2bf(oa0.w*inv);
        w0[4]=(short)f2bf(oa1.x*inv); w0[5]=(short)f2bf(oa1.y*inv);
        w0[6]=(short)f2bf(oa1.z*inv); w0[7]=(short)f2bf(oa1.w*inv);
        w1[0]=(short)f2bf(oa2.x*inv); w1[1]=(short)f2bf(oa2.y*inv);
        w1[2]=(short)f2bf(oa2.z*inv); w1[3]=(short)f2bf(oa2.w*inv);
        w1[4]=(short)f2bf(oa3.x*inv); w1[5]=(short)f2bf(oa3.y*inv);
        w1[6]=(short)f2bf(oa3.z*inv); w1[7]=(short)f2bf(oa3.w*inv);
        short* op = obf + s*BROW + h*16;
        *(bf16x8*)op = w0;  *(bf16x8*)(op + 8) = w1;
      }
    }
    __syncthreads();

    // ======== out-proj + y: wave handles 1 n-tile x 2 m-tiles ========
    {
      const short* ap = obf + (rb + n16)*BROW + kg8;
      bf16x8 A00 = *(const bf16x8*)(ap);            bf16x8 A01 = *(const bf16x8*)(ap + 32);
      bf16x8 A10 = *(const bf16x8*)(ap + 16*BROW);  bf16x8 A11 = *(const bf16x8*)(ap + 16*BROW + 32);
      const int nt = wg;
      const short* bp = wF + (size_t)(48 + l*8 + nt*2)*512 + lane*8;
      bf16x8 B0 = *(const bf16x8*)(bp);
      bf16x8 B1 = *(const bf16x8*)(bp + 512);
      f32x4 c0={0,0,0,0}, c1={0,0,0,0};
      c0 = __builtin_amdgcn_mfma_f32_16x16x32_bf16(A00, B0, c0, 0,0,0);
      c0 = __builtin_amdgcn_mfma_f32_16x16x32_bf16(A01, B1, c0, 0,0,0);
      c1 = __builtin_amdgcn_mfma_f32_16x16x32_bf16(A10, B0, c1, 0,0,0);
      c1 = __builtin_amdgcn_mfma_f32_16x16x32_bf16(A11, B1, c1, 0,0,0);
      const int c = nt*16 + n16;
      const float bias = out_b[l*64 + c];
      #pragma unroll
      for (int r = 0; r < 4; ++r) {
        const int r0 = rb + mrow + r;
        const int r1 = r0 + 16;
        arena[r0*68 + c] = xf[r0*64 + c] + bias + c0[r];
        if (r1 < SHORTN) arena[r1*68 + c] = xf[r1*64 + c] + bias + c1[r];
      }
      for (int idx = tid; idx < 14*F1ROW; idx += 512) f1bf[50*F1ROW + idx] = 0;
    }
    __syncthreads();

    // ======== LN1 (8 waves) ========
    {
      const float g = ln1_g[l*64 + lane], bb = ln1_b[l*64 + lane];
      for (int s = w8; s < SHORTN; s += 8) {
        float y = arena[s*68 + lane];
        float mean = wave_sum(y) * (1.f/64.f);
        float dv = y - mean;
        float var = wave_sum(dv*dv) * (1.f/64.f);
        float r = dv / sqrtf(var + 1e-5f) * g + bb;
        xf[s*64 + lane] = r;
        xbf[s*BROW + lane] = (short)f2bf(r);
      }
    }
    __syncthreads();

    // ======== ff1: wave handles 2 n-tiles x 2 m-tiles ========
    {
      const short* ap = xbf + (rb + n16)*BROW + kg8;
      bf16x8 A00 = *(const bf16x8*)(ap);            bf16x8 A01 = *(const bf16x8*)(ap + 32);
      bf16x8 A10 = *(const bf16x8*)(ap + 16*BROW);  bf16x8 A11 = *(const bf16x8*)(ap + 16*BROW + 32);
      #pragma unroll
      for (int t = 0; t < 2; ++t) {
        const int nt = wg*2 + t;
        const short* bp = wF + (size_t)(64 + l*16 + nt*2)*512 + lane*8;
        bf16x8 B0 = *(const bf16x8*)(bp);
        bf16x8 B1 = *(const bf16x8*)(bp + 512);
        f32x4 c0={0,0,0,0}, c1={0,0,0,0};
        c0 = __builtin_amdgcn_mfma_f32_16x16x32_bf16(A00, B0, c0, 0,0,0);
        c0 = __builtin_amdgcn_mfma_f32_16x16x32_bf16(A01, B1, c0, 0,0,0);
        c1 = __builtin_amdgcn_mfma_f32_16x16x32_bf16(A10, B0, c1, 0,0,0);
        c1 = __builtin_amdgcn_mfma_f32_16x16x32_bf16(A11, B1, c1, 0,0,0);
        const int c = nt*16 + n16;
        const float bias = ff1_b[l*128 + c];
        #pragma unroll
        for (int r = 0; r < 4; ++r) {
          const int r0 = rb + mrow + r;
          const int r1 = r0 + 16;
          f1bf[r0*F1ROW + c] = (short)f2bf(fmaxf(c0[r] + bias, 0.f));
          if (r1 < SHORTN) f1bf[r1*F1ROW + c] = (short)f2bf(fmaxf(c1[r] + bias, 0.f));
        }
      }
    }
    __syncthreads();

    // ======== ff2: wave handles 1 n-tile x 2 m-tiles, K=128 ========
    {
      const int nt = wg;
      f32x4 c0={0,0,0,0}, c1={0,0,0,0};
      #pragma unroll
      for (int kc = 0; kc < 4; ++kc) {
        const short* ap = f1bf + (rb + n16)*F1ROW + kc*32 + kg8;
        bf16x8 A0 = *(const bf16x8*)(ap);
        bf16x8 A1 = *(const bf16x8*)(ap + 16*F1ROW);
        const short* bp = wF + (size_t)(96 + l*16 + nt*4 + kc)*512 + lane*8;
        bf16x8 B = *(const bf16x8*)(bp);
        c0 = __builtin_amdgcn_mfma_f32_16x16x32_bf16(A0, B, c0, 0,0,0);
        c1 = __builtin_amdgcn_mfma_f32_16x16x32_bf16(A1, B, c1, 0,0,0);
      }
      __syncthreads();
      const int c = nt*16 + n16;
      const float bias = ff2_b[l*64 + c];
      #pragma unroll
      for (int r = 0; r < 4; ++r) {
        const int r0 = rb + mrow + r;
        const int r1 = r0 + 16;
        arena[r0*68 + c] = xf[r0*64 + c] + bias + c0[r];
        if (r1 < SHORTN) arena[r1*68 + c] = xf[r1*64 + c] + bias + c1[r];
      }
    }
    __syncthreads();

    // ======== LN2 (8 waves) ========
    {
      const float g = ln2_g[l*64 + lane], bb = ln2_b[l*64 + lane];
      for (int s = w8; s < SHORTN; s += 8) {
        float y = arena[s*68 + lane];
        float mean = wave_sum(y) * (1.f/64.f);
        float dv = y - mean;
        float var = wave_sum(dv*dv) * (1.f/64.f);
        float r = dv / sqrtf(var + 1e-5f) * g + bb;
        xf[s*64 + lane] = r;
        xbf[s*BROW + lane] = (short)f2bf(r);
      }
    }
    __syncthreads();
  }

  float acc = 0.f;
  for (int s = w8; s < SHORTN; s += 8) acc += xf[s*64 + lane];
  qf[w8*64 + lane] = acc;
  __syncthreads();
  if (w8 == 0) {
    float t = qf[lane];
    #pragma unroll
    for (int w = 1; w < 8; ++w) t += qf[w*64 + lane];
    bst_out[b*64 + lane] = t * (1.f/50.f);
  }
}

// ===========================================================================
// K2+K4 merged, 512 threads: softmax(1000) + bitonic top-50 + re-softmax +
// hard/soft repr in LDS + fusion MLP. grid = NB.
// ===========================================================================
__global__ __launch_bounds__(512) void hard_finish_fusion_kernel(
    const int* __restrict__ long_hist_ids,
    const float* __restrict__ item_emb,
    const float* __restrict__ sdim_w, const float* __restrict__ sdim_b,
    const float* __restrict__ scores_ws,
    const float* __restrict__ partA, const float* __restrict__ partH,
    const float* __restrict__ user, const float* __restrict__ bst,
    const float* __restrict__ w1, const float* __restrict__ b1,
    const float* __restrict__ w2, const float* __restrict__ b2,
    const float* __restrict__ w3, const float* __restrict__ b3,
    float* __restrict__ out)
{
  __shared__ __align__(16) float scores[LONGN];
  __shared__ int   idsL[LONGN];
  __shared__ __align__(16) unsigned long long kv[1024];
  __shared__ __align__(16) float redE[8*64];
  __shared__ __align__(16) float vecbuf[64];
  __shared__ float redV[8];
  __shared__ float selV[TOPKN];
  __shared__ int   selI[TOPKN];
  __shared__ __align__(16) float comb[256];
  __shared__ __align__(16) float h1[256];
  __shared__ __align__(16) float h2[128];

  const int b = blockIdx.x;
  const int tid = threadIdx.x;
  const int wid = tid >> 6, lane = tid & 63;

  for (int l = tid; l < LONGN; l += 512) {
    scores[l] = scores_ws[b*LONGN + l];
    idsL[l] = long_hist_ids[b*LONGN + l];
  }
  if (tid < 64)                          comb[tid] = user[b*64 + tid];
  else if (tid >= 192 && tid < 256)      comb[tid] = bst[b*64 + tid - 192];
  __syncthreads();

  // ---- soft_repr -> comb[128..192) ----
  if (tid < 64)
    vecbuf[tid] = (partA[(2*b)*64 + tid] + partA[(2*b+1)*64 + tid]
                 + partH[(2*b)*64 + tid] + partH[(2*b+1)*64 + tid]) * (1.f/1000.f);
  __syncthreads();
  if (tid < 64)
    comb[128 + tid] = sdim_b[tid] + dotN<64>(sdim_w + tid*64, vecbuf);

  // ---- softmax over 1000 ----
  float mx = -INFINITY;
  for (int l = tid; l < LONGN; l += 512) mx = fmaxf(mx, scores[l]);
  mx = wave_max(mx);
  if (lane == 0) redV[wid] = mx;
  __syncthreads();
  mx = redV[0];
  #pragma unroll
  for (int w = 1; w < 8; ++w) mx = fmaxf(mx, redV[w]);
  __syncthreads();
  float sm = 0.f;
  for (int l = tid; l < LONGN; l += 512) {
    float a = expf(scores[l] - mx);
    scores[l] = a;
    sm += a;
  }
  sm = wave_sum(sm);
  if (lane == 0) redV[wid] = sm;
  __syncthreads();
  {
    float tot = redV[0];
    #pragma unroll
    for (int w = 1; w < 8; ++w) tot += redV[w];
    const float inv = 1.f / tot;
    for (int l = tid; l < LONGN; l += 512) scores[l] *= inv;
  }
  __syncthreads();

  // ---- composite keys + bitonic sort (1 exchange/thread/stage) ----
  for (int l = tid; l < 1024; l += 512) {
    if (l < LONGN) {
      unsigned vb = __float_as_uint(scores[l]);
      kv[l] = ((unsigned long long)(~vb) << 32) | (unsigned)l;
    } else {
      kv[l] = 0xFFFFFFFFFFFFFFFFull;
    }
  }
  __syncthreads();

  for (int k = 2; k <= 1024; k <<= 1) {
    for (int j = k >> 1; j > 0; j >>= 1) {
      {
        const int p = tid;
        const int i = ((p & ~(j-1)) << 1) | (p & (j-1));
        const int m = i + j;
        const bool up = ((i & k) == 0);
        unsigned long long a = kv[i], c = kv[m];
        if ((a > c) == up) { kv[i] = c; kv[m] = a; }
      }
      __syncthreads();
    }
  }

  if (tid < TOPKN) {
    unsigned long long key = kv[tid];
    selI[tid] = (int)(unsigned)(key & 0xFFFFFFFFu);
    selV[tid] = __uint_as_float(~(unsigned)(key >> 32));
  }
  __syncthreads();

  // ---- softmax over the 50 selected ----
  if (wid == 0) {
    float v = (lane < TOPKN) ? selV[lane] : -INFINITY;
    float m2 = wave_max(v);
    float e = (lane < TOPKN) ? expf(v - m2) : 0.f;
    float s2 = wave_sum(e);
    if (lane < TOPKN) selV[lane] = e / s2;
  }
  __syncthreads();

  // ---- hard_repr -> comb[64..128) ----
  float accR = 0.f;
  for (int r = wid; r < TOPKN; r += 8)
    accR += selV[r] * item_emb[idsL[selI[r]]*64 + lane];
  redE[wid*64 + lane] = accR;
  __syncthreads();
  if (wid == 0) {
    float t = redE[lane];
    #pragma unroll
    for (int w = 1; w < 8; ++w) t += redE[w*64 + lane];
    comb[64 + lane] = t;
  }
  __syncthreads();

  // ---- fusion MLP ----
  if (tid < 256) h1[tid] = fmaxf(b1[tid] + dotN<256>(w1 + tid*256, comb), 0.f);
  __syncthreads();
  if (tid < 128) h2[tid] = fmaxf(b2[tid] + dotN<256>(w2 + tid*256, h1), 0.f);
  __syncthreads();
  if (tid < 64) {
    float p = w3[tid]*h2[tid] + w3[tid+64]*h2[tid+64];
    p = wave_sum(p);
    if (tid == 0) out[b] = p + b3[0];
  }
}

extern "C" void kernel_launch(void* const* d_in, const int* in_sizes, int n_in,
                              void* d_out, int out_size, void* d_ws, size_t ws_size,
                              hipStream_t stream) {
  const float* user_features  = (const float*)d_in[0];
  const int*   target_item_id = (const int*)  d_in[1];
  const int*   short_hist_ids = (const int*)  d_in[2];
  const int*   long_hist_ids  = (const int*)  d_in[3];
  const float* item_emb       = (const float*)d_in[4];
  const float* tproj_w  = (const float*)d_in[5];
  const float* tproj_b  = (const float*)d_in[6];
  const float* attn_w1  = (const float*)d_in[7];
  const float* attn_b1  = (const float*)d_in[8];
  const float* attn_w2  = (const float*)d_in[9];
  const float* attn_b2  = (const float*)d_in[10];
  const float* hash_emb = (const float*)d_in[11];
  const float* sdim_w   = (const float*)d_in[12];
  const float* sdim_b   = (const float*)d_in[13];
  const float* tf_qkv_w = (const float*)d_in[14];
  const float* tf_qkv_b = (const float*)d_in[15];
  const float* tf_out_w = (const float*)d_in[16];
  const float* tf_out_b = (const float*)d_in[17];
  const float* tf_ln1_g = (const float*)d_in[18];
  const float* tf_ln1_b = (const float*)d_in[19];
  const float* tf_ff1_w = (const float*)d_in[20];
  const float* tf_ff1_b = (const float*)d_in[21];
  const float* tf_ff2_w = (const float*)d_in[22];
  const float* tf_ff2_b = (const float*)d_in[23];
  const float* tf_ln2_g = (const float*)d_in[24];
  const float* tf_ln2_b = (const float*)d_in[25];
  const float* fus_w1   = (const float*)d_in[26];
  const float* fus_b1   = (const float*)d_in[27];
  const float* fus_w2   = (const float*)d_in[28];
  const float* fus_b2   = (const float*)d_in[29];
  const float* fus_w3   = (const float*)d_in[30];
  const float* fus_b3   = (const float*)d_in[31];

  float* ws = (float*)d_ws;
  float* hard = ws;                    // NB*64 (unused, kept for layout)
  float* soft = hard + NB*64;          // NB*64 (unused)
  float* bst  = soft + NB*64;          // NB*64
  float* scores_ws = bst + NB*64;      // NB*1000
  float* partA = scores_ws + NB*LONGN; // NB*2*64
  float* partH = partA + NB*2*64;      // NB*2*64
  short* wF    = (short*)(partH + NB*2*64); // 65536 shorts (128 KB)

  bst_prep_kernel<<<32, 256, 0, stream>>>(tf_qkv_w, tf_out_w, tf_ff1_w, tf_ff2_w, wF);
  hard_scores_kernel<<<2*NB, 256, 0, stream>>>(target_item_id, long_hist_ids,
      item_emb, tproj_w, tproj_b, attn_w1, attn_b1, attn_w2, attn_b2,
      hash_emb, scores_ws, partA, partH);
  bst_kernel<<<NB, 512, 0, stream>>>(short_hist_ids, item_emb, wF,
      tf_qkv_b, tf_out_b, tf_ln1_g, tf_ln1_b, tf_ff1_b, tf_ff2_b,
      tf_ln2_g, tf_ln2_b, bst);
  hard_finish_fusion_kernel<<<NB, 512, 0, stream>>>(long_hist_ids, item_emb,
      sdim_w, sdim_b, scores_ws, partA, partH,
      user_features, bst, fus_w1, fus_b1, fus_w2, fus_b2, fus_w3, fus_b3,
      (float*)d_out);
}